// Round 1
// baseline (3498.082 us; speedup 1.0000x reference)
//
#include <hip/hip_runtime.h>

#define NN 10000
#define EE 80000
#define TT 10

// ---------------------------------------------------------------------------
// Block = 256 threads, processes 32 rows through a fused 3-layer MLP (+LN).
// Thread tid owns cols j0..j0+3 (j0=(tid&31)*4) of rows r0..r0+3 (r0=(tid>>5)*4).
// LN reduction = __shfl_xor over the 32-lane half-wave that shares a row set.
// ---------------------------------------------------------------------------

__device__ __forceinline__ void initacc(const float* __restrict__ b, int tid, float acc[4][4]) {
  const int j0 = (tid & 31) * 4;
  float4 b4 = *(const float4*)(b + j0);
  #pragma unroll
  for (int rr = 0; rr < 4; ++rr) {
    acc[rr][0] = b4.x; acc[rr][1] = b4.y; acc[rr][2] = b4.z; acc[rr][3] = b4.w;
  }
}

template<int K, int SX, bool RELU>
__device__ __forceinline__ void gemm32(const float* __restrict__ W,
                                       const float* __restrict__ b,
                                       const float* __restrict__ xs,
                                       float acc[4][4], int tid) {
  const int j0 = (tid & 31) * 4;
  const int r0 = (tid >> 5) * 4;
  initacc(b, tid, acc);
  constexpr int KV = K & ~3;
  #pragma unroll 2
  for (int k = 0; k < KV; k += 4) {
    float4 x[4];
    #pragma unroll
    for (int rr = 0; rr < 4; ++rr) x[rr] = *(const float4*)(xs + (r0 + rr) * SX + k);
    #pragma unroll
    for (int kk = 0; kk < 4; ++kk) {
      float4 w = *(const float4*)(W + (size_t)(k + kk) * 128 + j0);
      #pragma unroll
      for (int rr = 0; rr < 4; ++rr) {
        float xv = (kk == 0) ? x[rr].x : (kk == 1) ? x[rr].y : (kk == 2) ? x[rr].z : x[rr].w;
        acc[rr][0] = fmaf(xv, w.x, acc[rr][0]);
        acc[rr][1] = fmaf(xv, w.y, acc[rr][1]);
        acc[rr][2] = fmaf(xv, w.z, acc[rr][2]);
        acc[rr][3] = fmaf(xv, w.w, acc[rr][3]);
      }
    }
  }
  for (int k = KV; k < K; ++k) {   // scalar K tail (K=30, K=3)
    float4 w = *(const float4*)(W + (size_t)k * 128 + j0);
    #pragma unroll
    for (int rr = 0; rr < 4; ++rr) {
      float xv = xs[(r0 + rr) * SX + k];
      acc[rr][0] = fmaf(xv, w.x, acc[rr][0]);
      acc[rr][1] = fmaf(xv, w.y, acc[rr][1]);
      acc[rr][2] = fmaf(xv, w.z, acc[rr][2]);
      acc[rr][3] = fmaf(xv, w.w, acc[rr][3]);
    }
  }
  if (RELU) {
    #pragma unroll
    for (int rr = 0; rr < 4; ++rr)
      #pragma unroll
      for (int c = 0; c < 4; ++c)
        acc[rr][c] = acc[rr][c] > 0.f ? acc[rr][c] : 0.f;
  }
}

__device__ __forceinline__ void store32(const float acc[4][4], float* out, int tid) {
  const int j0 = (tid & 31) * 4;
  const int r0 = (tid >> 5) * 4;
  #pragma unroll
  for (int rr = 0; rr < 4; ++rr) {
    float4 v = {acc[rr][0], acc[rr][1], acc[rr][2], acc[rr][3]};
    *(float4*)(out + (r0 + rr) * 128 + j0) = v;
  }
}

// LayerNorm over 128 cols of each row (eps = 1e-3, keras default).
__device__ __forceinline__ void ln32(float acc[4][4], const float* __restrict__ g,
                                     const float* __restrict__ be, int tid) {
  const int j0 = (tid & 31) * 4;
  float4 g4  = *(const float4*)(g + j0);
  float4 be4 = *(const float4*)(be + j0);
  #pragma unroll
  for (int rr = 0; rr < 4; ++rr) {
    float s = acc[rr][0] + acc[rr][1] + acc[rr][2] + acc[rr][3];
    float q = acc[rr][0]*acc[rr][0] + acc[rr][1]*acc[rr][1]
            + acc[rr][2]*acc[rr][2] + acc[rr][3]*acc[rr][3];
    #pragma unroll
    for (int m = 1; m < 32; m <<= 1) {
      s += __shfl_xor(s, m, 32);
      q += __shfl_xor(q, m, 32);
    }
    float mean = s * (1.f / 128.f);
    float var  = q * (1.f / 128.f) - mean * mean;
    float inv  = rsqrtf(var + 1e-3f);
    acc[rr][0] = g4.x * (acc[rr][0] - mean) * inv + be4.x;
    acc[rr][1] = g4.y * (acc[rr][1] - mean) * inv + be4.y;
    acc[rr][2] = g4.z * (acc[rr][2] - mean) * inv + be4.z;
    acc[rr][3] = g4.w * (acc[rr][3] - mean) * inv + be4.w;
  }
}

// ---------------------------------------------------------------------------
// node encoder: [N,30] -> MLP(30->128->128->128) -> LN -> h
__global__ __launch_bounds__(256) void enc_node_k(
    const float* __restrict__ nf,
    const float* __restrict__ W0, const float* __restrict__ b0,
    const float* __restrict__ W1, const float* __restrict__ b1,
    const float* __restrict__ W2, const float* __restrict__ b2,
    const float* __restrict__ g,  const float* __restrict__ be,
    float* __restrict__ h) {
  __shared__ float xs[32 * 32];
  __shared__ float hb[2][32 * 128];
  const int tid = threadIdx.x;
  const int row0 = blockIdx.x * 32;
  for (int i = tid; i < 32 * 30; i += 256) {
    int r = i / 30, c = i - r * 30;
    int gr = row0 + r;
    xs[r * 32 + c] = (gr < NN) ? nf[(size_t)gr * 30 + c] : 0.f;
  }
  __syncthreads();
  float acc[4][4];
  gemm32<30, 32, true>(W0, b0, xs, acc, tid);  store32(acc, hb[0], tid); __syncthreads();
  gemm32<128, 128, true>(W1, b1, hb[0], acc, tid); store32(acc, hb[1], tid); __syncthreads();
  gemm32<128, 128, false>(W2, b2, hb[1], acc, tid);
  ln32(acc, g, be, tid);
  const int j0 = (tid & 31) * 4, r0 = (tid >> 5) * 4;
  #pragma unroll
  for (int rr = 0; rr < 4; ++rr) {
    int gr = row0 + r0 + rr;
    if (gr < NN) {
      float4 v = {acc[rr][0], acc[rr][1], acc[rr][2], acc[rr][3]};
      *(float4*)(h + (size_t)gr * 128 + j0) = v;
    }
  }
}

// edge encoder: [E,3] -> MLP(3->128->128->128) -> LN -> e
__global__ __launch_bounds__(256) void enc_edge_k(
    const float* __restrict__ ef,
    const float* __restrict__ W0, const float* __restrict__ b0,
    const float* __restrict__ W1, const float* __restrict__ b1,
    const float* __restrict__ W2, const float* __restrict__ b2,
    const float* __restrict__ g,  const float* __restrict__ be,
    float* __restrict__ e) {
  __shared__ float xs[32 * 4];
  __shared__ float hb[2][32 * 128];
  const int tid = threadIdx.x;
  const int row0 = blockIdx.x * 32;       // E % 32 == 0, no guards
  for (int i = tid; i < 32 * 3; i += 256) {
    int r = i / 3, c = i - r * 3;
    xs[r * 4 + c] = ef[(size_t)(row0 + r) * 3 + c];
  }
  __syncthreads();
  float acc[4][4];
  gemm32<3, 4, true>(W0, b0, xs, acc, tid);  store32(acc, hb[0], tid); __syncthreads();
  gemm32<128, 128, true>(W1, b1, hb[0], acc, tid); store32(acc, hb[1], tid); __syncthreads();
  gemm32<128, 128, false>(W2, b2, hb[1], acc, tid);
  ln32(acc, g, be, tid);
  const int j0 = (tid & 31) * 4, r0 = (tid >> 5) * 4;
  #pragma unroll
  for (int rr = 0; rr < 4; ++rr) {
    float4 v = {acc[rr][0], acc[rr][1], acc[rr][2], acc[rr][3]};
    *(float4*)(e + (size_t)(row0 + r0 + rr) * 128 + j0) = v;
  }
}

// msg: gather [h[rcv], h[snd], e] -> MLP(384->128->128->128) -> LN
//      -> atomicAdd into pooled[rcv]
__global__ __launch_bounds__(256) void msg_k(
    const float* __restrict__ h, const float* __restrict__ e,
    const int* __restrict__ snd, const int* __restrict__ rcv,
    const float* __restrict__ W0, const float* __restrict__ b0,
    const float* __restrict__ W1, const float* __restrict__ b1,
    const float* __restrict__ W2, const float* __restrict__ b2,
    const float* __restrict__ g,  const float* __restrict__ be,
    float* __restrict__ pooled) {
  __shared__ float xs[32 * 384];          // 48 KB
  __shared__ float hb0[32 * 128];         // 16 KB   (total 64 KB)
  float* hb1 = xs;                        // layer1 output aliases xs (dead after layer0)
  const int tid = threadIdx.x;
  const int row0 = blockIdx.x * 32;       // E % 32 == 0
  for (int q = tid; q < 32 * 96; q += 256) {
    int r = q / 96, c = q - (q / 96) * 96;
    int ge = row0 + r;
    const float* src;
    if (c < 32)      src = h + (size_t)rcv[ge] * 128 + c * 4;
    else if (c < 64) src = h + (size_t)snd[ge] * 128 + (c - 32) * 4;
    else             src = e + (size_t)ge * 128 + (c - 64) * 4;
    *(float4*)(xs + r * 384 + c * 4) = *(const float4*)src;
  }
  __syncthreads();
  float acc[4][4];
  gemm32<384, 384, true>(W0, b0, xs, acc, tid);  store32(acc, hb0, tid); __syncthreads();
  gemm32<128, 128, true>(W1, b1, hb0, acc, tid); store32(acc, hb1, tid); __syncthreads();
  gemm32<128, 128, false>(W2, b2, hb1, acc, tid);
  ln32(acc, g, be, tid);
  const int j0 = (tid & 31) * 4, r0 = (tid >> 5) * 4;
  #pragma unroll
  for (int rr = 0; rr < 4; ++rr) {
    int dst = rcv[row0 + r0 + rr];
    #pragma unroll
    for (int c = 0; c < 4; ++c)
      atomicAdd(pooled + (size_t)dst * 128 + j0 + c, acc[rr][c]);
  }
}

// upd: [h, pooled] -> MLP(256->128->128->128) -> LN -> h += .
__global__ __launch_bounds__(256) void upd_k(
    float* __restrict__ h, const float* __restrict__ pooled,
    const float* __restrict__ W0, const float* __restrict__ b0,
    const float* __restrict__ W1, const float* __restrict__ b1,
    const float* __restrict__ W2, const float* __restrict__ b2,
    const float* __restrict__ g,  const float* __restrict__ be) {
  __shared__ float xs[32 * 256];          // 32 KB
  __shared__ float hb[2][32 * 128];       // 32 KB  (total 64 KB)
  const int tid = threadIdx.x;
  const int row0 = blockIdx.x * 32;
  for (int q = tid; q < 32 * 64; q += 256) {
    int r = q >> 6, c = q & 63;
    int gn = row0 + r;
    float4 v = {0.f, 0.f, 0.f, 0.f};
    if (gn < NN)
      v = (c < 32) ? *(const float4*)(h + (size_t)gn * 128 + c * 4)
                   : *(const float4*)(pooled + (size_t)gn * 128 + (c - 32) * 4);
    *(float4*)(xs + r * 256 + c * 4) = v;
  }
  __syncthreads();
  float acc[4][4];
  gemm32<256, 256, true>(W0, b0, xs, acc, tid);   store32(acc, hb[0], tid); __syncthreads();
  gemm32<128, 128, true>(W1, b1, hb[0], acc, tid); store32(acc, hb[1], tid); __syncthreads();
  gemm32<128, 128, false>(W2, b2, hb[1], acc, tid);
  ln32(acc, g, be, tid);
  const int j0 = (tid & 31) * 4, r0 = (tid >> 5) * 4;
  #pragma unroll
  for (int rr = 0; rr < 4; ++rr) {
    int gn = row0 + r0 + rr;
    if (gn < NN) {
      float4 v;
      v.x = xs[(r0 + rr) * 256 + j0 + 0] + acc[rr][0];
      v.y = xs[(r0 + rr) * 256 + j0 + 1] + acc[rr][1];
      v.z = xs[(r0 + rr) * 256 + j0 + 2] + acc[rr][2];
      v.w = xs[(r0 + rr) * 256 + j0 + 3] + acc[rr][3];
      *(float4*)(h + (size_t)gn * 128 + j0) = v;
    }
  }
}

// decoder: h -> MLP(128->128->128->3) -> out
__global__ __launch_bounds__(256) void dec_k(
    const float* __restrict__ h,
    const float* __restrict__ W0, const float* __restrict__ b0,
    const float* __restrict__ W1, const float* __restrict__ b1,
    const float* __restrict__ W2, const float* __restrict__ b2,
    float* __restrict__ out) {
  __shared__ float xs[32 * 128];          // 16 KB
  __shared__ float hb0[32 * 128];         // 16 KB
  float* hb1 = xs;                        // alias: xs dead after layer0
  const int tid = threadIdx.x;
  const int row0 = blockIdx.x * 32;
  for (int q = tid; q < 32 * 32; q += 256) {
    int r = q >> 5, c = q & 31;
    int gn = row0 + r;
    float4 v = {0.f, 0.f, 0.f, 0.f};
    if (gn < NN) v = *(const float4*)(h + (size_t)gn * 128 + c * 4);
    *(float4*)(xs + r * 128 + c * 4) = v;
  }
  __syncthreads();
  float acc[4][4];
  gemm32<128, 128, true>(W0, b0, xs, acc, tid);  store32(acc, hb0, tid); __syncthreads();
  gemm32<128, 128, true>(W1, b1, hb0, acc, tid); store32(acc, hb1, tid); __syncthreads();
  if (tid < 96) {
    int r = tid / 3, o = tid - (tid / 3) * 3;
    int gn = row0 + r;
    float a = b2[o];
    for (int k = 0; k < 128; ++k) a = fmaf(hb1[r * 128 + k], W2[k * 3 + o], a);
    if (gn < NN) out[(size_t)gn * 3 + o] = a;
  }
}

// ---------------------------------------------------------------------------
extern "C" void kernel_launch(void* const* d_in, const int* in_sizes, int n_in,
                              void* d_out, int out_size, void* d_ws, size_t ws_size,
                              hipStream_t stream) {
  int i = 0;
  const float* node_feat = (const float*)d_in[i++];
  const float* edge_feat = (const float*)d_in[i++];
  const int*   senders   = (const int*)d_in[i++];
  const int*   receivers = (const int*)d_in[i++];
  const float *encn_W0 = (const float*)d_in[i++], *encn_b0 = (const float*)d_in[i++],
              *encn_W1 = (const float*)d_in[i++], *encn_b1 = (const float*)d_in[i++],
              *encn_W2 = (const float*)d_in[i++], *encn_b2 = (const float*)d_in[i++],
              *encn_g  = (const float*)d_in[i++], *encn_be = (const float*)d_in[i++];
  const float *ence_W0 = (const float*)d_in[i++], *ence_b0 = (const float*)d_in[i++],
              *ence_W1 = (const float*)d_in[i++], *ence_b1 = (const float*)d_in[i++],
              *ence_W2 = (const float*)d_in[i++], *ence_b2 = (const float*)d_in[i++],
              *ence_g  = (const float*)d_in[i++], *ence_be = (const float*)d_in[i++];
  const float *msg_W0 = (const float*)d_in[i++], *msg_b0 = (const float*)d_in[i++],
              *msg_W1 = (const float*)d_in[i++], *msg_b1 = (const float*)d_in[i++],
              *msg_W2 = (const float*)d_in[i++], *msg_b2 = (const float*)d_in[i++],
              *msg_g  = (const float*)d_in[i++], *msg_be = (const float*)d_in[i++];
  const float *upd_W0 = (const float*)d_in[i++], *upd_b0 = (const float*)d_in[i++],
              *upd_W1 = (const float*)d_in[i++], *upd_b1 = (const float*)d_in[i++],
              *upd_W2 = (const float*)d_in[i++], *upd_b2 = (const float*)d_in[i++],
              *upd_g  = (const float*)d_in[i++], *upd_be = (const float*)d_in[i++];
  const float *dec_W0 = (const float*)d_in[i++], *dec_b0 = (const float*)d_in[i++],
              *dec_W1 = (const float*)d_in[i++], *dec_b1 = (const float*)d_in[i++],
              *dec_W2 = (const float*)d_in[i++], *dec_b2 = (const float*)d_in[i++];

  float* h      = (float*)d_ws;                 // [N,128]
  float* pooled = h + (size_t)NN * 128;         // [N,128]
  float* e      = pooled + (size_t)NN * 128;    // [E,128]   total ~51 MB

  const int NB_N = (NN + 31) / 32;   // 313
  const int NB_E = EE / 32;          // 2500

  enc_node_k<<<NB_N, 256, 0, stream>>>(node_feat, encn_W0, encn_b0, encn_W1, encn_b1,
                                       encn_W2, encn_b2, encn_g, encn_be, h);
  enc_edge_k<<<NB_E, 256, 0, stream>>>(edge_feat, ence_W0, ence_b0, ence_W1, ence_b1,
                                       ence_W2, ence_b2, ence_g, ence_be, e);
  for (int t = 0; t < TT; ++t) {
    hipMemsetAsync(pooled, 0, (size_t)NN * 128 * sizeof(float), stream);
    msg_k<<<NB_E, 256, 0, stream>>>(h, e, senders, receivers,
        msg_W0 + (size_t)t * 384 * 128, msg_b0 + (size_t)t * 128,
        msg_W1 + (size_t)t * 128 * 128, msg_b1 + (size_t)t * 128,
        msg_W2 + (size_t)t * 128 * 128, msg_b2 + (size_t)t * 128,
        msg_g + (size_t)t * 128, msg_be + (size_t)t * 128, pooled);
    upd_k<<<NB_N, 256, 0, stream>>>(h, pooled,
        upd_W0 + (size_t)t * 256 * 128, upd_b0 + (size_t)t * 128,
        upd_W1 + (size_t)t * 128 * 128, upd_b1 + (size_t)t * 128,
        upd_W2 + (size_t)t * 128 * 128, upd_b2 + (size_t)t * 128,
        upd_g + (size_t)t * 128, upd_be + (size_t)t * 128);
  }
  dec_k<<<NB_N, 256, 0, stream>>>(h, dec_W0, dec_b0, dec_W1, dec_b1, dec_W2, dec_b2,
                                  (float*)d_out);
}

// Round 2
// 2799.083 us; speedup vs baseline: 1.2497x; 1.2497x over previous
//
#include <hip/hip_runtime.h>

#define NN 10000
#define EE 80000
#define TT 10

typedef unsigned short u16;
typedef unsigned int u32;
using f32x4  = __attribute__((ext_vector_type(4))) float;
using bf16x8 = __attribute__((ext_vector_type(8))) short;

__device__ __forceinline__ u16 f2bf(float f) {
  union { float f; u32 u; } v; v.f = f;
  return (u16)((v.u + 0x7fffu + ((v.u >> 16) & 1u)) >> 16);   // RNE
}

// ===========================================================================
// fp32 path (encoders / upd / dec) — unchanged structure from round 1
// ===========================================================================

__device__ __forceinline__ void initacc(const float* __restrict__ b, int tid, float acc[4][4]) {
  const int j0 = (tid & 31) * 4;
  float4 b4 = *(const float4*)(b + j0);
  #pragma unroll
  for (int rr = 0; rr < 4; ++rr) {
    acc[rr][0] = b4.x; acc[rr][1] = b4.y; acc[rr][2] = b4.z; acc[rr][3] = b4.w;
  }
}

template<int K, int SX, bool RELU>
__device__ __forceinline__ void gemm32(const float* __restrict__ W,
                                       const float* __restrict__ b,
                                       const float* __restrict__ xs,
                                       float acc[4][4], int tid) {
  const int j0 = (tid & 31) * 4;
  const int r0 = (tid >> 5) * 4;
  initacc(b, tid, acc);
  constexpr int KV = K & ~3;
  #pragma unroll 2
  for (int k = 0; k < KV; k += 4) {
    float4 x[4];
    #pragma unroll
    for (int rr = 0; rr < 4; ++rr) x[rr] = *(const float4*)(xs + (r0 + rr) * SX + k);
    #pragma unroll
    for (int kk = 0; kk < 4; ++kk) {
      float4 w = *(const float4*)(W + (size_t)(k + kk) * 128 + j0);
      #pragma unroll
      for (int rr = 0; rr < 4; ++rr) {
        float xv = (kk == 0) ? x[rr].x : (kk == 1) ? x[rr].y : (kk == 2) ? x[rr].z : x[rr].w;
        acc[rr][0] = fmaf(xv, w.x, acc[rr][0]);
        acc[rr][1] = fmaf(xv, w.y, acc[rr][1]);
        acc[rr][2] = fmaf(xv, w.z, acc[rr][2]);
        acc[rr][3] = fmaf(xv, w.w, acc[rr][3]);
      }
    }
  }
  for (int k = KV; k < K; ++k) {
    float4 w = *(const float4*)(W + (size_t)k * 128 + j0);
    #pragma unroll
    for (int rr = 0; rr < 4; ++rr) {
      float xv = xs[(r0 + rr) * SX + k];
      acc[rr][0] = fmaf(xv, w.x, acc[rr][0]);
      acc[rr][1] = fmaf(xv, w.y, acc[rr][1]);
      acc[rr][2] = fmaf(xv, w.z, acc[rr][2]);
      acc[rr][3] = fmaf(xv, w.w, acc[rr][3]);
    }
  }
  if (RELU) {
    #pragma unroll
    for (int rr = 0; rr < 4; ++rr)
      #pragma unroll
      for (int c = 0; c < 4; ++c)
        acc[rr][c] = acc[rr][c] > 0.f ? acc[rr][c] : 0.f;
  }
}

__device__ __forceinline__ void store32(const float acc[4][4], float* out, int tid) {
  const int j0 = (tid & 31) * 4;
  const int r0 = (tid >> 5) * 4;
  #pragma unroll
  for (int rr = 0; rr < 4; ++rr) {
    float4 v = {acc[rr][0], acc[rr][1], acc[rr][2], acc[rr][3]};
    *(float4*)(out + (r0 + rr) * 128 + j0) = v;
  }
}

__device__ __forceinline__ void ln32(float acc[4][4], const float* __restrict__ g,
                                     const float* __restrict__ be, int tid) {
  const int j0 = (tid & 31) * 4;
  float4 g4  = *(const float4*)(g + j0);
  float4 be4 = *(const float4*)(be + j0);
  #pragma unroll
  for (int rr = 0; rr < 4; ++rr) {
    float s = acc[rr][0] + acc[rr][1] + acc[rr][2] + acc[rr][3];
    float q = acc[rr][0]*acc[rr][0] + acc[rr][1]*acc[rr][1]
            + acc[rr][2]*acc[rr][2] + acc[rr][3]*acc[rr][3];
    #pragma unroll
    for (int m = 1; m < 32; m <<= 1) {
      s += __shfl_xor(s, m, 32);
      q += __shfl_xor(q, m, 32);
    }
    float mean = s * (1.f / 128.f);
    float var  = q * (1.f / 128.f) - mean * mean;
    float inv  = rsqrtf(var + 1e-3f);
    acc[rr][0] = g4.x * (acc[rr][0] - mean) * inv + be4.x;
    acc[rr][1] = g4.y * (acc[rr][1] - mean) * inv + be4.y;
    acc[rr][2] = g4.z * (acc[rr][2] - mean) * inv + be4.z;
    acc[rr][3] = g4.w * (acc[rr][3] - mean) * inv + be4.w;
  }
}

// node encoder -> h (fp32) + h_bf (bf16)
__global__ __launch_bounds__(256) void enc_node_k(
    const float* __restrict__ nf,
    const float* __restrict__ W0, const float* __restrict__ b0,
    const float* __restrict__ W1, const float* __restrict__ b1,
    const float* __restrict__ W2, const float* __restrict__ b2,
    const float* __restrict__ g,  const float* __restrict__ be,
    float* __restrict__ h, u16* __restrict__ h_bf) {
  __shared__ float xs[32 * 32];
  __shared__ float hb[2][32 * 128];
  const int tid = threadIdx.x;
  const int row0 = blockIdx.x * 32;
  for (int i = tid; i < 32 * 30; i += 256) {
    int r = i / 30, c = i - r * 30;
    int gr = row0 + r;
    xs[r * 32 + c] = (gr < NN) ? nf[(size_t)gr * 30 + c] : 0.f;
  }
  __syncthreads();
  float acc[4][4];
  gemm32<30, 32, true>(W0, b0, xs, acc, tid);  store32(acc, hb[0], tid); __syncthreads();
  gemm32<128, 128, true>(W1, b1, hb[0], acc, tid); store32(acc, hb[1], tid); __syncthreads();
  gemm32<128, 128, false>(W2, b2, hb[1], acc, tid);
  ln32(acc, g, be, tid);
  const int j0 = (tid & 31) * 4, r0 = (tid >> 5) * 4;
  #pragma unroll
  for (int rr = 0; rr < 4; ++rr) {
    int gr = row0 + r0 + rr;
    if (gr < NN) {
      float4 v = {acc[rr][0], acc[rr][1], acc[rr][2], acc[rr][3]};
      *(float4*)(h + (size_t)gr * 128 + j0) = v;
      ushort4 o;
      o.x = f2bf(acc[rr][0]); o.y = f2bf(acc[rr][1]);
      o.z = f2bf(acc[rr][2]); o.w = f2bf(acc[rr][3]);
      *(ushort4*)(h_bf + (size_t)gr * 128 + j0) = o;
    }
  }
}

// edge encoder -> e_bf (bf16 only; msg is the sole consumer)
__global__ __launch_bounds__(256) void enc_edge_k(
    const float* __restrict__ ef,
    const float* __restrict__ W0, const float* __restrict__ b0,
    const float* __restrict__ W1, const float* __restrict__ b1,
    const float* __restrict__ W2, const float* __restrict__ b2,
    const float* __restrict__ g,  const float* __restrict__ be,
    u16* __restrict__ e_bf) {
  __shared__ float xs[32 * 4];
  __shared__ float hb[2][32 * 128];
  const int tid = threadIdx.x;
  const int row0 = blockIdx.x * 32;
  for (int i = tid; i < 32 * 3; i += 256) {
    int r = i / 3, c = i - r * 3;
    xs[r * 4 + c] = ef[(size_t)(row0 + r) * 3 + c];
  }
  __syncthreads();
  float acc[4][4];
  gemm32<3, 4, true>(W0, b0, xs, acc, tid);  store32(acc, hb[0], tid); __syncthreads();
  gemm32<128, 128, true>(W1, b1, hb[0], acc, tid); store32(acc, hb[1], tid); __syncthreads();
  gemm32<128, 128, false>(W2, b2, hb[1], acc, tid);
  ln32(acc, g, be, tid);
  const int j0 = (tid & 31) * 4, r0 = (tid >> 5) * 4;
  #pragma unroll
  for (int rr = 0; rr < 4; ++rr) {
    ushort4 o;
    o.x = f2bf(acc[rr][0]); o.y = f2bf(acc[rr][1]);
    o.z = f2bf(acc[rr][2]); o.w = f2bf(acc[rr][3]);
    *(ushort4*)(e_bf + (size_t)(row0 + r0 + rr) * 128 + j0) = o;
  }
}

// upd: [h, pooled] -> MLP -> LN -> h += .   (fp32; also refresh h_bf)
__global__ __launch_bounds__(256) void upd_k(
    float* __restrict__ h, const float* __restrict__ pooled,
    const float* __restrict__ W0, const float* __restrict__ b0,
    const float* __restrict__ W1, const float* __restrict__ b1,
    const float* __restrict__ W2, const float* __restrict__ b2,
    const float* __restrict__ g,  const float* __restrict__ be,
    u16* __restrict__ h_bf) {
  __shared__ float xs[32 * 256];
  __shared__ float hb[2][32 * 128];
  const int tid = threadIdx.x;
  const int row0 = blockIdx.x * 32;
  for (int q = tid; q < 32 * 64; q += 256) {
    int r = q >> 6, c = q & 63;
    int gn = row0 + r;
    float4 v = {0.f, 0.f, 0.f, 0.f};
    if (gn < NN)
      v = (c < 32) ? *(const float4*)(h + (size_t)gn * 128 + c * 4)
                   : *(const float4*)(pooled + (size_t)gn * 128 + (c - 32) * 4);
    *(float4*)(xs + r * 256 + c * 4) = v;
  }
  __syncthreads();
  float acc[4][4];
  gemm32<256, 256, true>(W0, b0, xs, acc, tid);   store32(acc, hb[0], tid); __syncthreads();
  gemm32<128, 128, true>(W1, b1, hb[0], acc, tid); store32(acc, hb[1], tid); __syncthreads();
  gemm32<128, 128, false>(W2, b2, hb[1], acc, tid);
  ln32(acc, g, be, tid);
  const int j0 = (tid & 31) * 4, r0 = (tid >> 5) * 4;
  #pragma unroll
  for (int rr = 0; rr < 4; ++rr) {
    int gn = row0 + r0 + rr;
    if (gn < NN) {
      float4 v;
      v.x = xs[(r0 + rr) * 256 + j0 + 0] + acc[rr][0];
      v.y = xs[(r0 + rr) * 256 + j0 + 1] + acc[rr][1];
      v.z = xs[(r0 + rr) * 256 + j0 + 2] + acc[rr][2];
      v.w = xs[(r0 + rr) * 256 + j0 + 3] + acc[rr][3];
      *(float4*)(h + (size_t)gn * 128 + j0) = v;
      ushort4 o;
      o.x = f2bf(v.x); o.y = f2bf(v.y); o.z = f2bf(v.z); o.w = f2bf(v.w);
      *(ushort4*)(h_bf + (size_t)gn * 128 + j0) = o;
    }
  }
}

// decoder: h -> MLP(128->128->128->3) -> out  (fp32)
__global__ __launch_bounds__(256) void dec_k(
    const float* __restrict__ h,
    const float* __restrict__ W0, const float* __restrict__ b0,
    const float* __restrict__ W1, const float* __restrict__ b1,
    const float* __restrict__ W2, const float* __restrict__ b2,
    float* __restrict__ out) {
  __shared__ float xs[32 * 128];
  __shared__ float hb0[32 * 128];
  float* hb1 = xs;
  const int tid = threadIdx.x;
  const int row0 = blockIdx.x * 32;
  for (int q = tid; q < 32 * 32; q += 256) {
    int r = q >> 5, c = q & 31;
    int gn = row0 + r;
    float4 v = {0.f, 0.f, 0.f, 0.f};
    if (gn < NN) v = *(const float4*)(h + (size_t)gn * 128 + c * 4);
    *(float4*)(xs + r * 128 + c * 4) = v;
  }
  __syncthreads();
  float acc[4][4];
  gemm32<128, 128, true>(W0, b0, xs, acc, tid);  store32(acc, hb0, tid); __syncthreads();
  gemm32<128, 128, true>(W1, b1, hb0, acc, tid); store32(acc, hb1, tid); __syncthreads();
  if (tid < 96) {
    int r = tid / 3, o = tid - (tid / 3) * 3;
    int gn = row0 + r;
    float a = b2[o];
    for (int k = 0; k < 128; ++k) a = fmaf(hb1[r * 128 + k], W2[k * 3 + o], a);
    if (gn < NN) out[(size_t)gn * 3 + o] = a;
  }
}

// ===========================================================================
// bf16 MFMA msg path
// ===========================================================================

// W^T pre-transpose+convert: dst[t][n][k] = bf16(src[t][k][n])
__global__ __launch_bounds__(256) void wtrans_k(const float* __restrict__ src,
                                                u16* __restrict__ dst, int K) {
  __shared__ float tile[32][33];
  const int tiles_per_t = (K / 32) * 4;
  const int t  = blockIdx.x / tiles_per_t;
  const int rem = blockIdx.x - t * tiles_per_t;
  const int kt = rem >> 2, nt = rem & 3;
  const float* s = src + (size_t)t * K * 128;
  u16* d = dst + (size_t)t * 128 * K;
  const int r = threadIdx.x >> 5, c = threadIdx.x & 31;
  for (int rr = r; rr < 32; rr += 8)
    tile[rr][c] = s[(size_t)(kt * 32 + rr) * 128 + nt * 32 + c];
  __syncthreads();
  for (int rr = r; rr < 32; rr += 8)
    d[(size_t)(nt * 32 + rr) * K + kt * 32 + c] = f2bf(tile[c][rr]);
}

#define XSTR 392   // 384 + 8 pad (bf16 elems): row stride 784B -> even bank spread
#define HSTR 136   // 128 + 8 pad

// One fused MLP layer on MFMA, operands swapped:
//   A = W-tile (rows = output channels, from global W^T, 8 contig k per lane)
//   B = X-tile (cols = edges, from LDS row-major, 8 contig k per lane)
//   D: row = channel = lq*4+i within tile ct, col = edge = lane&15
template<int K>
__device__ __forceinline__ void mfma_layer(
    const u16* xrow, int xstr,
    const u16* __restrict__ Wt, const float* __restrict__ bias,
    f32x4 acc[8], int l15, int lq) {
  #pragma unroll
  for (int ct = 0; ct < 8; ++ct)
    acc[ct] = *(const f32x4*)(bias + ct * 16 + lq * 4);
  const u16* xp = xrow + l15 * xstr + lq * 8;
  const u16* wp = Wt + (size_t)l15 * K + lq * 8;
  #pragma unroll 2
  for (int k0 = 0; k0 < K; k0 += 32) {
    bf16x8 xf = *(const bf16x8*)(xp + k0);
    #pragma unroll
    for (int ct = 0; ct < 8; ++ct) {
      bf16x8 wf = *(const bf16x8*)(wp + (size_t)ct * 16 * K + k0);
      acc[ct] = __builtin_amdgcn_mfma_f32_16x16x32_bf16(wf, xf, acc[ct], 0, 0, 0);
    }
  }
}

__device__ __forceinline__ void relu_store_bf(const f32x4 acc[8], u16* out,
                                              int hstr, int l15, int lq) {
  #pragma unroll
  for (int ct = 0; ct < 8; ++ct) {
    ushort4 o;
    o.x = f2bf(fmaxf(acc[ct][0], 0.f));
    o.y = f2bf(fmaxf(acc[ct][1], 0.f));
    o.z = f2bf(fmaxf(acc[ct][2], 0.f));
    o.w = f2bf(fmaxf(acc[ct][3], 0.f));
    *(ushort4*)(out + l15 * hstr + ct * 16 + lq * 4) = o;
  }
}

// msg: gather -> MLP(384->128->128->128) bf16 MFMA -> LN(fp32) -> atomic pooled
// 64 edges/block, 4 independent waves (16 edges each), NO barriers.
__global__ __launch_bounds__(256, 3) void msg_mfma_k(
    const u16* __restrict__ h_bf, const u16* __restrict__ e_bf,
    const int* __restrict__ snd, const int* __restrict__ rcv,
    const u16* __restrict__ Wt0, const float* __restrict__ b0,
    const u16* __restrict__ Wt1, const float* __restrict__ b1,
    const u16* __restrict__ Wt2, const float* __restrict__ b2,
    const float* __restrict__ g,  const float* __restrict__ be,
    float* __restrict__ pooled) {
  __shared__ u16 xs[64 * XSTR];          // 50176 B -> 3 blocks/CU
  const int tid  = threadIdx.x;
  const int lane = tid & 63;
  const int wv   = tid >> 6;
  const int er0  = wv * 16;              // this wave's first edge row in block
  const int row0 = blockIdx.x * 64;
  const int l15  = lane & 15;
  const int lq   = lane >> 4;

  // ---- gather [h[rcv] | h[snd] | e] as bf16: 16 rows x 48 chunks x 16B ----
  for (int q = lane; q < 16 * 48; q += 64) {
    int r = q / 48, c = q - (q / 48) * 48;
    int ge = row0 + er0 + r;
    const u16* src;
    if (c < 16)       src = h_bf + (size_t)rcv[ge] * 128 + c * 8;
    else if (c < 32)  src = h_bf + (size_t)snd[ge] * 128 + (c - 16) * 8;
    else              src = e_bf + (size_t)ge * 128 + (c - 32) * 8;
    *(uint4*)(xs + (er0 + r) * XSTR + c * 8) = *(const uint4*)src;
  }
  // wave-local producer/consumer: compiler's lgkmcnt ordering suffices, no barrier

  u16* Wl  = xs + er0 * XSTR;   // this wave's private 12544B region
  u16* hb1 = Wl;                // [16][HSTR] aliases own xs (dead after L0 k-loop)
  u16* hb2 = Wl + 16 * HSTR;    // disjoint from hb1, still within own region

  f32x4 acc[8];
  mfma_layer<384>(Wl,  XSTR, Wt0, b0, acc, l15, lq);
  relu_store_bf(acc, hb1, HSTR, l15, lq);
  mfma_layer<128>(hb1, HSTR, Wt1, b1, acc, l15, lq);
  relu_store_bf(acc, hb2, HSTR, l15, lq);
  mfma_layer<128>(hb2, HSTR, Wt2, b2, acc, l15, lq);

  // ---- LayerNorm over 128 channels of edge (row0+er0+l15), fp32 ----
  float s = 0.f, qq = 0.f;
  #pragma unroll
  for (int ct = 0; ct < 8; ++ct)
    #pragma unroll
    for (int i = 0; i < 4; ++i) { float v = acc[ct][i]; s += v; qq += v * v; }
  s  += __shfl_xor(s, 16, 64);  s  += __shfl_xor(s, 32, 64);
  qq += __shfl_xor(qq, 16, 64); qq += __shfl_xor(qq, 32, 64);
  float mean = s * (1.f / 128.f);
  float var  = qq * (1.f / 128.f) - mean * mean;
  float inv  = rsqrtf(var + 1e-3f);

  int dst = rcv[row0 + er0 + l15];
  float* pp = pooled + (size_t)dst * 128;
  #pragma unroll
  for (int ct = 0; ct < 8; ++ct) {
    f32x4 g4 = *(const f32x4*)(g  + ct * 16 + lq * 4);
    f32x4 b4 = *(const f32x4*)(be + ct * 16 + lq * 4);
    #pragma unroll
    for (int i = 0; i < 4; ++i) {
      float v = g4[i] * (acc[ct][i] - mean) * inv + b4[i];
      atomicAdd(pp + ct * 16 + lq * 4 + i, v);
    }
  }
}

// ===========================================================================
extern "C" void kernel_launch(void* const* d_in, const int* in_sizes, int n_in,
                              void* d_out, int out_size, void* d_ws, size_t ws_size,
                              hipStream_t stream) {
  int i = 0;
  const float* node_feat = (const float*)d_in[i++];
  const float* edge_feat = (const float*)d_in[i++];
  const int*   senders   = (const int*)d_in[i++];
  const int*   receivers = (const int*)d_in[i++];
  const float *encn_W0 = (const float*)d_in[i++], *encn_b0 = (const float*)d_in[i++],
              *encn_W1 = (const float*)d_in[i++], *encn_b1 = (const float*)d_in[i++],
              *encn_W2 = (const float*)d_in[i++], *encn_b2 = (const float*)d_in[i++],
              *encn_g  = (const float*)d_in[i++], *encn_be = (const float*)d_in[i++];
  const float *ence_W0 = (const float*)d_in[i++], *ence_b0 = (const float*)d_in[i++],
              *ence_W1 = (const float*)d_in[i++], *ence_b1 = (const float*)d_in[i++],
              *ence_W2 = (const float*)d_in[i++], *ence_b2 = (const float*)d_in[i++],
              *ence_g  = (const float*)d_in[i++], *ence_be = (const float*)d_in[i++];
  const float *msg_W0 = (const float*)d_in[i++], *msg_b0 = (const float*)d_in[i++],
              *msg_W1 = (const float*)d_in[i++], *msg_b1 = (const float*)d_in[i++],
              *msg_W2 = (const float*)d_in[i++], *msg_b2 = (const float*)d_in[i++],
              *msg_g  = (const float*)d_in[i++], *msg_be = (const float*)d_in[i++];
  const float *upd_W0 = (const float*)d_in[i++], *upd_b0 = (const float*)d_in[i++],
              *upd_W1 = (const float*)d_in[i++], *upd_b1 = (const float*)d_in[i++],
              *upd_W2 = (const float*)d_in[i++], *upd_b2 = (const float*)d_in[i++],
              *upd_g  = (const float*)d_in[i++], *upd_be = (const float*)d_in[i++];
  const float *dec_W0 = (const float*)d_in[i++], *dec_b0 = (const float*)d_in[i++],
              *dec_W1 = (const float*)d_in[i++], *dec_b1 = (const float*)d_in[i++],
              *dec_W2 = (const float*)d_in[i++], *dec_b2 = (const float*)d_in[i++];

  // workspace layout (~36 MB; round-1 used 51 MB successfully)
  float* h      = (float*)d_ws;                          // [N,128] f32
  float* pooled = h + (size_t)NN * 128;                  // [N,128] f32
  u16*   h_bf   = (u16*)(pooled + (size_t)NN * 128);     // [N,128] bf16
  u16*   e_bf   = h_bf + (size_t)NN * 128;               // [E,128] bf16
  u16*   Wt0    = e_bf + (size_t)EE * 128;               // [10][128][384] bf16
  u16*   Wt1    = Wt0 + (size_t)10 * 128 * 384;          // [10][128][128]
  u16*   Wt2    = Wt1 + (size_t)10 * 128 * 128;          // [10][128][128]

  const int NB_N = (NN + 31) / 32;   // 313
  const int NB_E32 = EE / 32;        // 2500
  const int NB_E64 = EE / 64;        // 1250

  // weight pre-transpose (bf16 W^T), per launch
  wtrans_k<<<10 * (384 / 32) * 4, 256, 0, stream>>>(msg_W0, Wt0, 384);
  wtrans_k<<<10 * (128 / 32) * 4, 256, 0, stream>>>(msg_W1, Wt1, 128);
  wtrans_k<<<10 * (128 / 32) * 4, 256, 0, stream>>>(msg_W2, Wt2, 128);

  enc_node_k<<<NB_N, 256, 0, stream>>>(node_feat, encn_W0, encn_b0, encn_W1, encn_b1,
                                       encn_W2, encn_b2, encn_g, encn_be, h, h_bf);
  enc_edge_k<<<NB_E32, 256, 0, stream>>>(edge_feat, ence_W0, ence_b0, ence_W1, ence_b1,
                                         ence_W2, ence_b2, ence_g, ence_be, e_bf);
  for (int t = 0; t < TT; ++t) {
    hipMemsetAsync(pooled, 0, (size_t)NN * 128 * sizeof(float), stream);
    msg_mfma_k<<<NB_E64, 256, 0, stream>>>(h_bf, e_bf, senders, receivers,
        Wt0 + (size_t)t * 128 * 384, msg_b0 + (size_t)t * 128,
        Wt1 + (size_t)t * 128 * 128, msg_b1 + (size_t)t * 128,
        Wt2 + (size_t)t * 128 * 128, msg_b2 + (size_t)t * 128,
        msg_g + (size_t)t * 128, msg_be + (size_t)t * 128, pooled);
    upd_k<<<NB_N, 256, 0, stream>>>(h, pooled,
        upd_W0 + (size_t)t * 256 * 128, upd_b0 + (size_t)t * 128,
        upd_W1 + (size_t)t * 128 * 128, upd_b1 + (size_t)t * 128,
        upd_W2 + (size_t)t * 128 * 128, upd_b2 + (size_t)t * 128,
        upd_g + (size_t)t * 128, upd_be + (size_t)t * 128, h_bf);
  }
  dec_k<<<NB_N, 256, 0, stream>>>(h, dec_W0, dec_b0, dec_W1, dec_b1, dec_W2, dec_b2,
                                  (float*)d_out);
}

// Round 3
// 1015.732 us; speedup vs baseline: 3.4439x; 2.7557x over previous
//
#include <hip/hip_runtime.h>

#define NN 10000
#define EE 80000
#define TT 10

typedef unsigned short u16;
typedef unsigned int u32;
using f32x4  = __attribute__((ext_vector_type(4))) float;
using bf16x8 = __attribute__((ext_vector_type(8))) short;

__device__ __forceinline__ u16 f2bf(float f) {
  union { float f; u32 u; } v; v.f = f;
  return (u16)((v.u + 0x7fffu + ((v.u >> 16) & 1u)) >> 16);   // RNE
}
__device__ __forceinline__ float bflo(u32 v) { union { u32 u; float f; } x; x.u = v << 16; return x.f; }
__device__ __forceinline__ float bfhi(u32 v) { union { u32 u; float f; } x; x.u = v & 0xffff0000u; return x.f; }

// ===========================================================================
// fp32 path (encoders / upd / dec) — unchanged from round 2
// ===========================================================================

__device__ __forceinline__ void initacc(const float* __restrict__ b, int tid, float acc[4][4]) {
  const int j0 = (tid & 31) * 4;
  float4 b4 = *(const float4*)(b + j0);
  #pragma unroll
  for (int rr = 0; rr < 4; ++rr) {
    acc[rr][0] = b4.x; acc[rr][1] = b4.y; acc[rr][2] = b4.z; acc[rr][3] = b4.w;
  }
}

template<int K, int SX, bool RELU>
__device__ __forceinline__ void gemm32(const float* __restrict__ W,
                                       const float* __restrict__ b,
                                       const float* __restrict__ xs,
                                       float acc[4][4], int tid) {
  const int j0 = (tid & 31) * 4;
  const int r0 = (tid >> 5) * 4;
  initacc(b, tid, acc);
  constexpr int KV = K & ~3;
  #pragma unroll 2
  for (int k = 0; k < KV; k += 4) {
    float4 x[4];
    #pragma unroll
    for (int rr = 0; rr < 4; ++rr) x[rr] = *(const float4*)(xs + (r0 + rr) * SX + k);
    #pragma unroll
    for (int kk = 0; kk < 4; ++kk) {
      float4 w = *(const float4*)(W + (size_t)(k + kk) * 128 + j0);
      #pragma unroll
      for (int rr = 0; rr < 4; ++rr) {
        float xv = (kk == 0) ? x[rr].x : (kk == 1) ? x[rr].y : (kk == 2) ? x[rr].z : x[rr].w;
        acc[rr][0] = fmaf(xv, w.x, acc[rr][0]);
        acc[rr][1] = fmaf(xv, w.y, acc[rr][1]);
        acc[rr][2] = fmaf(xv, w.z, acc[rr][2]);
        acc[rr][3] = fmaf(xv, w.w, acc[rr][3]);
      }
    }
  }
  for (int k = KV; k < K; ++k) {
    float4 w = *(const float4*)(W + (size_t)k * 128 + j0);
    #pragma unroll
    for (int rr = 0; rr < 4; ++rr) {
      float xv = xs[(r0 + rr) * SX + k];
      acc[rr][0] = fmaf(xv, w.x, acc[rr][0]);
      acc[rr][1] = fmaf(xv, w.y, acc[rr][1]);
      acc[rr][2] = fmaf(xv, w.z, acc[rr][2]);
      acc[rr][3] = fmaf(xv, w.w, acc[rr][3]);
    }
  }
  if (RELU) {
    #pragma unroll
    for (int rr = 0; rr < 4; ++rr)
      #pragma unroll
      for (int c = 0; c < 4; ++c)
        acc[rr][c] = acc[rr][c] > 0.f ? acc[rr][c] : 0.f;
  }
}

__device__ __forceinline__ void store32(const float acc[4][4], float* out, int tid) {
  const int j0 = (tid & 31) * 4;
  const int r0 = (tid >> 5) * 4;
  #pragma unroll
  for (int rr = 0; rr < 4; ++rr) {
    float4 v = {acc[rr][0], acc[rr][1], acc[rr][2], acc[rr][3]};
    *(float4*)(out + (r0 + rr) * 128 + j0) = v;
  }
}

__device__ __forceinline__ void ln32(float acc[4][4], const float* __restrict__ g,
                                     const float* __restrict__ be, int tid) {
  const int j0 = (tid & 31) * 4;
  float4 g4  = *(const float4*)(g + j0);
  float4 be4 = *(const float4*)(be + j0);
  #pragma unroll
  for (int rr = 0; rr < 4; ++rr) {
    float s = acc[rr][0] + acc[rr][1] + acc[rr][2] + acc[rr][3];
    float q = acc[rr][0]*acc[rr][0] + acc[rr][1]*acc[rr][1]
            + acc[rr][2]*acc[rr][2] + acc[rr][3]*acc[rr][3];
    #pragma unroll
    for (int m = 1; m < 32; m <<= 1) {
      s += __shfl_xor(s, m, 32);
      q += __shfl_xor(q, m, 32);
    }
    float mean = s * (1.f / 128.f);
    float var  = q * (1.f / 128.f) - mean * mean;
    float inv  = rsqrtf(var + 1e-3f);
    acc[rr][0] = g4.x * (acc[rr][0] - mean) * inv + be4.x;
    acc[rr][1] = g4.y * (acc[rr][1] - mean) * inv + be4.y;
    acc[rr][2] = g4.z * (acc[rr][2] - mean) * inv + be4.z;
    acc[rr][3] = g4.w * (acc[rr][3] - mean) * inv + be4.w;
  }
}

__global__ __launch_bounds__(256) void enc_node_k(
    const float* __restrict__ nf,
    const float* __restrict__ W0, const float* __restrict__ b0,
    const float* __restrict__ W1, const float* __restrict__ b1,
    const float* __restrict__ W2, const float* __restrict__ b2,
    const float* __restrict__ g,  const float* __restrict__ be,
    float* __restrict__ h, u16* __restrict__ h_bf) {
  __shared__ float xs[32 * 32];
  __shared__ float hb[2][32 * 128];
  const int tid = threadIdx.x;
  const int row0 = blockIdx.x * 32;
  for (int i = tid; i < 32 * 30; i += 256) {
    int r = i / 30, c = i - r * 30;
    int gr = row0 + r;
    xs[r * 32 + c] = (gr < NN) ? nf[(size_t)gr * 30 + c] : 0.f;
  }
  __syncthreads();
  float acc[4][4];
  gemm32<30, 32, true>(W0, b0, xs, acc, tid);  store32(acc, hb[0], tid); __syncthreads();
  gemm32<128, 128, true>(W1, b1, hb[0], acc, tid); store32(acc, hb[1], tid); __syncthreads();
  gemm32<128, 128, false>(W2, b2, hb[1], acc, tid);
  ln32(acc, g, be, tid);
  const int j0 = (tid & 31) * 4, r0 = (tid >> 5) * 4;
  #pragma unroll
  for (int rr = 0; rr < 4; ++rr) {
    int gr = row0 + r0 + rr;
    if (gr < NN) {
      float4 v = {acc[rr][0], acc[rr][1], acc[rr][2], acc[rr][3]};
      *(float4*)(h + (size_t)gr * 128 + j0) = v;
      ushort4 o;
      o.x = f2bf(acc[rr][0]); o.y = f2bf(acc[rr][1]);
      o.z = f2bf(acc[rr][2]); o.w = f2bf(acc[rr][3]);
      *(ushort4*)(h_bf + (size_t)gr * 128 + j0) = o;
    }
  }
}

__global__ __launch_bounds__(256) void enc_edge_k(
    const float* __restrict__ ef,
    const float* __restrict__ W0, const float* __restrict__ b0,
    const float* __restrict__ W1, const float* __restrict__ b1,
    const float* __restrict__ W2, const float* __restrict__ b2,
    const float* __restrict__ g,  const float* __restrict__ be,
    u16* __restrict__ e_bf) {
  __shared__ float xs[32 * 4];
  __shared__ float hb[2][32 * 128];
  const int tid = threadIdx.x;
  const int row0 = blockIdx.x * 32;
  for (int i = tid; i < 32 * 3; i += 256) {
    int r = i / 3, c = i - r * 3;
    xs[r * 4 + c] = ef[(size_t)(row0 + r) * 3 + c];
  }
  __syncthreads();
  float acc[4][4];
  gemm32<3, 4, true>(W0, b0, xs, acc, tid);  store32(acc, hb[0], tid); __syncthreads();
  gemm32<128, 128, true>(W1, b1, hb[0], acc, tid); store32(acc, hb[1], tid); __syncthreads();
  gemm32<128, 128, false>(W2, b2, hb[1], acc, tid);
  ln32(acc, g, be, tid);
  const int j0 = (tid & 31) * 4, r0 = (tid >> 5) * 4;
  #pragma unroll
  for (int rr = 0; rr < 4; ++rr) {
    ushort4 o;
    o.x = f2bf(acc[rr][0]); o.y = f2bf(acc[rr][1]);
    o.z = f2bf(acc[rr][2]); o.w = f2bf(acc[rr][3]);
    *(ushort4*)(e_bf + (size_t)(row0 + r0 + rr) * 128 + j0) = o;
  }
}

__global__ __launch_bounds__(256) void upd_k(
    float* __restrict__ h, const float* __restrict__ pooled,
    const float* __restrict__ W0, const float* __restrict__ b0,
    const float* __restrict__ W1, const float* __restrict__ b1,
    const float* __restrict__ W2, const float* __restrict__ b2,
    const float* __restrict__ g,  const float* __restrict__ be,
    u16* __restrict__ h_bf) {
  __shared__ float xs[32 * 256];
  __shared__ float hb[2][32 * 128];
  const int tid = threadIdx.x;
  const int row0 = blockIdx.x * 32;
  for (int q = tid; q < 32 * 64; q += 256) {
    int r = q >> 6, c = q & 63;
    int gn = row0 + r;
    float4 v = {0.f, 0.f, 0.f, 0.f};
    if (gn < NN)
      v = (c < 32) ? *(const float4*)(h + (size_t)gn * 128 + c * 4)
                   : *(const float4*)(pooled + (size_t)gn * 128 + (c - 32) * 4);
    *(float4*)(xs + r * 256 + c * 4) = v;
  }
  __syncthreads();
  float acc[4][4];
  gemm32<256, 256, true>(W0, b0, xs, acc, tid);   store32(acc, hb[0], tid); __syncthreads();
  gemm32<128, 128, true>(W1, b1, hb[0], acc, tid); store32(acc, hb[1], tid); __syncthreads();
  gemm32<128, 128, false>(W2, b2, hb[1], acc, tid);
  ln32(acc, g, be, tid);
  const int j0 = (tid & 31) * 4, r0 = (tid >> 5) * 4;
  #pragma unroll
  for (int rr = 0; rr < 4; ++rr) {
    int gn = row0 + r0 + rr;
    if (gn < NN) {
      float4 v;
      v.x = xs[(r0 + rr) * 256 + j0 + 0] + acc[rr][0];
      v.y = xs[(r0 + rr) * 256 + j0 + 1] + acc[rr][1];
      v.z = xs[(r0 + rr) * 256 + j0 + 2] + acc[rr][2];
      v.w = xs[(r0 + rr) * 256 + j0 + 3] + acc[rr][3];
      *(float4*)(h + (size_t)gn * 128 + j0) = v;
      ushort4 o;
      o.x = f2bf(v.x); o.y = f2bf(v.y); o.z = f2bf(v.z); o.w = f2bf(v.w);
      *(ushort4*)(h_bf + (size_t)gn * 128 + j0) = o;
    }
  }
}

__global__ __launch_bounds__(256) void dec_k(
    const float* __restrict__ h,
    const float* __restrict__ W0, const float* __restrict__ b0,
    const float* __restrict__ W1, const float* __restrict__ b1,
    const float* __restrict__ W2, const float* __restrict__ b2,
    float* __restrict__ out) {
  __shared__ float xs[32 * 128];
  __shared__ float hb0[32 * 128];
  float* hb1 = xs;
  const int tid = threadIdx.x;
  const int row0 = blockIdx.x * 32;
  for (int q = tid; q < 32 * 32; q += 256) {
    int r = q >> 5, c = q & 31;
    int gn = row0 + r;
    float4 v = {0.f, 0.f, 0.f, 0.f};
    if (gn < NN) v = *(const float4*)(h + (size_t)gn * 128 + c * 4);
    *(float4*)(xs + r * 128 + c * 4) = v;
  }
  __syncthreads();
  float acc[4][4];
  gemm32<128, 128, true>(W0, b0, xs, acc, tid);  store32(acc, hb0, tid); __syncthreads();
  gemm32<128, 128, true>(W1, b1, hb0, acc, tid); store32(acc, hb1, tid); __syncthreads();
  if (tid < 96) {
    int r = tid / 3, o = tid - (tid / 3) * 3;
    int gn = row0 + r;
    float a = b2[o];
    for (int k = 0; k < 128; ++k) a = fmaf(hb1[r * 128 + k], W2[k * 3 + o], a);
    if (gn < NN) out[(size_t)gn * 3 + o] = a;
  }
}

// ===========================================================================
// CSR build (per-launch; deterministic work, fp-order noise only)
// ===========================================================================

__global__ __launch_bounds__(256) void hist_k(const int* __restrict__ rcv, int* __restrict__ cnt) {
  int e = blockIdx.x * 256 + threadIdx.x;
  if (e < EE) atomicAdd(&cnt[rcv[e]], 1);
}

__global__ __launch_bounds__(1024) void scan_k(const int* __restrict__ cnt,
                                               int* __restrict__ offs, int* __restrict__ curs) {
  __shared__ int ps[1024];
  const int t = threadIdx.x;
  int loc[10], s = 0;
  #pragma unroll
  for (int j = 0; j < 10; ++j) {
    int idx = t * 10 + j;
    int v = (idx < NN) ? cnt[idx] : 0;
    loc[j] = s; s += v;
  }
  ps[t] = s;
  __syncthreads();
  for (int off = 1; off < 1024; off <<= 1) {
    int v = (t >= off) ? ps[t - off] : 0;
    __syncthreads();
    ps[t] += v;
    __syncthreads();
  }
  int pre = (t == 0) ? 0 : ps[t - 1];
  #pragma unroll
  for (int j = 0; j < 10; ++j) {
    int idx = t * 10 + j;
    if (idx < NN) { int o = pre + loc[j]; offs[idx] = o; curs[idx] = o; }
  }
  if (t == 1023) offs[NN] = ps[1023];
}

__global__ __launch_bounds__(256) void scatter_k(const int* __restrict__ rcv,
                                                 int* __restrict__ curs, int* __restrict__ sortpos) {
  int e = blockIdx.x * 256 + threadIdx.x;
  if (e < EE) sortpos[e] = atomicAdd(&curs[rcv[e]], 1);
}

// segment-sum: one wave per node; m_buf rows are receiver-sorted -> contiguous
__global__ __launch_bounds__(256) void pool_k(const u16* __restrict__ m,
                                              const int* __restrict__ offs,
                                              float* __restrict__ pooled) {
  const int lane = threadIdx.x & 63;
  const int n = blockIdx.x * 4 + (threadIdx.x >> 6);
  const int j0 = offs[n], j1 = offs[n + 1];
  float a0 = 0.f, a1 = 0.f;
  int j = j0;
  for (; j + 4 <= j1; j += 4) {
    u32 v0 = *(const u32*)(m + (size_t)(j + 0) * 128 + lane * 2);
    u32 v1 = *(const u32*)(m + (size_t)(j + 1) * 128 + lane * 2);
    u32 v2 = *(const u32*)(m + (size_t)(j + 2) * 128 + lane * 2);
    u32 v3 = *(const u32*)(m + (size_t)(j + 3) * 128 + lane * 2);
    a0 += bflo(v0) + bflo(v1) + bflo(v2) + bflo(v3);
    a1 += bfhi(v0) + bfhi(v1) + bfhi(v2) + bfhi(v3);
  }
  for (; j < j1; ++j) {
    u32 v = *(const u32*)(m + (size_t)j * 128 + lane * 2);
    a0 += bflo(v); a1 += bfhi(v);
  }
  float2 o = {a0, a1};
  *(float2*)(pooled + (size_t)n * 128 + lane * 2) = o;
}

// ===========================================================================
// msg: tiled bf16 MFMA GEMM, 128 edges x 128 ch per block, BK=64, LDS-staged
// ===========================================================================

// W^T pre-transpose+convert: dst[t][n][k] = bf16(src[t][k][n])
__global__ __launch_bounds__(256) void wtrans_k(const float* __restrict__ src,
                                                u16* __restrict__ dst, int K) {
  __shared__ float tile[32][33];
  const int tiles_per_t = (K / 32) * 4;
  const int t  = blockIdx.x / tiles_per_t;
  const int rem = blockIdx.x - t * tiles_per_t;
  const int kt = rem >> 2, nt = rem & 3;
  const float* s = src + (size_t)t * K * 128;
  u16* d = dst + (size_t)t * 128 * K;
  const int r = threadIdx.x >> 5, c = threadIdx.x & 31;
  for (int rr = r; rr < 32; rr += 8)
    tile[rr][c] = s[(size_t)(kt * 32 + rr) * 128 + nt * 32 + c];
  __syncthreads();
  for (int rr = r; rr < 32; rr += 8)
    d[(size_t)(nt * 32 + rr) * K + kt * 32 + c] = f2bf(tile[c][rr]);
}

__global__ __launch_bounds__(256, 2) void msg_mfma_k(
    const u16* __restrict__ h_bf, const u16* __restrict__ e_bf,
    const int* __restrict__ snd, const int* __restrict__ rcv,
    const int* __restrict__ sortpos,
    const u16* __restrict__ Wt0, const float* __restrict__ b0,
    const u16* __restrict__ Wt1, const float* __restrict__ b1,
    const u16* __restrict__ Wt2, const float* __restrict__ b2,
    const float* __restrict__ g,  const float* __restrict__ be,
    u16* __restrict__ m_out) {
  // XS/WS: [buf][row 0..127][8 chunks of 16B], chunk index XOR-swizzled by row&7
  __shared__ u16 XS[2][128 * 64];
  __shared__ u16 WS[2][128 * 64];
  __shared__ float part_s[2][128], part_q[2][128];
  __shared__ int ir[128], is[128], sp[128];

  const int tid = threadIdx.x;
  const int lane = tid & 63;
  const int wq = tid >> 6;              // wave id (staging quarter)
  const int wm = wq >> 1, wn = wq & 1;  // compute tile: ch-half, edge-half
  const int l15 = lane & 15, lq = lane >> 4;
  const int row0 = blockIdx.x * 128;
  const int lr = lane >> 3;             // 0..7: row-within-8 for staging
  const int cj = lane & 7;              // 0..7: chunk for staging

  if (tid < 128) {
    ir[tid] = rcv[row0 + tid];
    is[tid] = snd[row0 + tid];
    sp[tid] = sortpos[row0 + tid];
  }
  __syncthreads();

  // ---- staging helpers (reg-staged: global -> VGPR -> swizzled ds_write) ----
  auto load_x = [&](int kt, uint4 v[4]) {
    #pragma unroll
    for (int i = 0; i < 4; ++i) {
      int q = wq * 32 + i * 8 + lr;           // edge-in-block
      const u16* base;
      if (kt < 2)      base = h_bf + (size_t)ir[q] * 128;
      else if (kt < 4) base = h_bf + (size_t)is[q] * 128;
      else             base = e_bf + (size_t)(row0 + q) * 128;
      v[i] = *(const uint4*)(base + (kt & 1) * 64 + cj * 8);
    }
  };
  auto load_w = [&](const u16* Wt, int kstr, int kt, uint4 v[4]) {
    #pragma unroll
    for (int i = 0; i < 4; ++i) {
      int ch = wq * 32 + i * 8 + lr;
      v[i] = *(const uint4*)(Wt + (size_t)ch * kstr + kt * 64 + cj * 8);
    }
  };
  auto stage = [&](u16 (*B)[128 * 64], int buf, const uint4 v[4]) {
    #pragma unroll
    for (int i = 0; i < 4; ++i) {
      int q = wq * 32 + i * 8 + lr;
      int c = cj ^ (lr & 7);
      *(uint4*)&B[buf][q * 64 + c * 8] = v[i];
    }
  };

  f32x4 acc[4][4];
  auto init_bias = [&](const float* b) {
    f32x4 bv[4];
    #pragma unroll
    for (int ct = 0; ct < 4; ++ct) bv[ct] = *(const f32x4*)(b + wm * 64 + ct * 16 + lq * 4);
    #pragma unroll
    for (int ct = 0; ct < 4; ++ct)
      #pragma unroll
      for (int et = 0; et < 4; ++et) acc[ct][et] = bv[ct];
  };
  auto compute_tile = [&](const u16* xbuf, const u16* wbuf) {
    #pragma unroll
    for (int k0 = 0; k0 < 2; ++k0) {
      bf16x8 wf[4], xf[4];
      #pragma unroll
      for (int ct = 0; ct < 4; ++ct) {
        int ch = wm * 64 + ct * 16 + l15;
        wf[ct] = *(const bf16x8*)&wbuf[ch * 64 + (((k0 * 4 + lq) ^ (l15 & 7)) * 8)];
      }
      #pragma unroll
      for (int et = 0; et < 4; ++et) {
        int ed = wn * 64 + et * 16 + l15;
        xf[et] = *(const bf16x8*)&xbuf[ed * 64 + (((k0 * 4 + lq) ^ (l15 & 7)) * 8)];
      }
      #pragma unroll
      for (int ct = 0; ct < 4; ++ct)
        #pragma unroll
        for (int et = 0; et < 4; ++et)
          acc[ct][et] = __builtin_amdgcn_mfma_f32_16x16x32_bf16(wf[ct], xf[et], acc[ct][et], 0, 0, 0);
    }
  };
  // write acc (optionally relu) as bf16 into XS[0..1] = [edge][128 k], swizzled
  auto store_h = [&](bool relu) {
    #pragma unroll
    for (int ct = 0; ct < 4; ++ct)
      #pragma unroll
      for (int et = 0; et < 4; ++et) {
        float v0 = acc[ct][et][0], v1 = acc[ct][et][1], v2 = acc[ct][et][2], v3 = acc[ct][et][3];
        if (relu) { v0 = fmaxf(v0, 0.f); v1 = fmaxf(v1, 0.f); v2 = fmaxf(v2, 0.f); v3 = fmaxf(v3, 0.f); }
        ushort4 o = {f2bf(v0), f2bf(v1), f2bf(v2), f2bf(v3)};
        int ed = wn * 64 + et * 16 + l15;
        int c3 = ct * 2 + (lq >> 1);
        int cs = c3 ^ (l15 & 7);
        *(ushort4*)&XS[wm][ed * 64 + cs * 8 + (lq & 1) * 4] = o;
      }
  };

  uint4 vx[4], vw[4];

  // ---------------- layer 0: K=384, 6 k-tiles ----------------
  init_bias(b0);
  load_x(0, vx); load_w(Wt0, 384, 0, vw);
  stage(XS, 0, vx); stage(WS, 0, vw);
  __syncthreads();
  for (int kt = 0; kt < 6; ++kt) {
    int cur = kt & 1, nxt = cur ^ 1;
    if (kt < 5) { load_x(kt + 1, vx); load_w(Wt0, 384, kt + 1, vw); }
    compute_tile(XS[cur], WS[cur]);
    if (kt < 5) { stage(XS, nxt, vx); stage(WS, nxt, vw); }
    __syncthreads();
  }
  store_h(true);          // h1 -> XS[0..1]
  __syncthreads();

  // ---------------- layer 1: K=128, 2 k-tiles ----------------
  init_bias(b1);
  load_w(Wt1, 128, 0, vw); stage(WS, 0, vw);
  __syncthreads();
  for (int kt = 0; kt < 2; ++kt) {
    if (kt < 1) load_w(Wt1, 128, 1, vw);
    compute_tile(XS[kt], WS[kt]);
    if (kt < 1) stage(WS, 1, vw);
    __syncthreads();
  }
  store_h(true);          // h2 -> XS[0..1]
  __syncthreads();

  // ---------------- layer 2: K=128, 2 k-tiles ----------------
  init_bias(b2);
  load_w(Wt2, 128, 0, vw); stage(WS, 0, vw);
  __syncthreads();
  for (int kt = 0; kt < 2; ++kt) {
    if (kt < 1) load_w(Wt2, 128, 1, vw);
    compute_tile(XS[kt], WS[kt]);
    if (kt < 1) stage(WS, 1, vw);
    __syncthreads();
  }

  // ---------------- LayerNorm (fp32, cross-wave over wm halves) ----------------
  float ss[4], qs[4];
  #pragma unroll
  for (int et = 0; et < 4; ++et) {
    float s = 0.f, q = 0.f;
    #pragma unroll
    for (int ct = 0; ct < 4; ++ct)
      #pragma unroll
      for (int i = 0; i < 4; ++i) { float v = acc[ct][et][i]; s += v; q += v * v; }
    s += __shfl_xor(s, 16, 64); s += __shfl_xor(s, 32, 64);
    q += __shfl_xor(q, 16, 64); q += __shfl_xor(q, 32, 64);
    ss[et] = s; qs[et] = q;
  }
  if (lane < 16) {
    #pragma unroll
    for (int et = 0; et < 4; ++et) {
      part_s[wm][wn * 64 + et * 16 + lane] = ss[et];
      part_q[wm][wn * 64 + et * 16 + lane] = qs[et];
    }
  }
  __syncthreads();
  float mean[4], inv[4];
  #pragma unroll
  for (int et = 0; et < 4; ++et) {
    int ed = wn * 64 + et * 16 + l15;
    float S = part_s[0][ed] + part_s[1][ed];
    float Q = part_q[0][ed] + part_q[1][ed];
    float m = S * (1.f / 128.f);
    float var = Q * (1.f / 128.f) - m * m;
    mean[et] = m; inv[et] = rsqrtf(var + 1e-3f);
  }
  #pragma unroll
  for (int ct = 0; ct < 4; ++ct) {
    f32x4 g4 = *(const f32x4*)(g  + wm * 64 + ct * 16 + lq * 4);
    f32x4 b4 = *(const f32x4*)(be + wm * 64 + ct * 16 + lq * 4);
    #pragma unroll
    for (int et = 0; et < 4; ++et)
      #pragma unroll
      for (int i = 0; i < 4; ++i)
        acc[ct][et][i] = g4[i] * (acc[ct][et][i] - mean[et]) * inv[et] + b4[i];
  }
  store_h(false);         // normalized m -> XS[0..1]
  __syncthreads();

  // ---------------- write out to m_buf[sortpos[e]] ----------------
  {
    int ed = tid >> 1, hf = tid & 1;
    size_t drow = (size_t)sp[ed] * 128;
    #pragma unroll
    for (int c = hf * 8; c < hf * 8 + 8; ++c) {
      int buf = c >> 3, c3 = c & 7, cs = c3 ^ (ed & 7);
      uint4 v = *(const uint4*)&XS[buf][ed * 64 + cs * 8];
      *(uint4*)(m_out + drow + c * 8) = v;
    }
  }
}

// ===========================================================================
extern "C" void kernel_launch(void* const* d_in, const int* in_sizes, int n_in,
                              void* d_out, int out_size, void* d_ws, size_t ws_size,
                              hipStream_t stream) {
  int i = 0;
  const float* node_feat = (const float*)d_in[i++];
  const float* edge_feat = (const float*)d_in[i++];
  const int*   senders   = (const int*)d_in[i++];
  const int*   receivers = (const int*)d_in[i++];
  const float *encn_W0 = (const float*)d_in[i++], *encn_b0 = (const float*)d_in[i++],
              *encn_W1 = (const float*)d_in[i++], *encn_b1 = (const float*)d_in[i++],
              *encn_W2 = (const float*)d_in[i++], *encn_b2 = (const float*)d_in[i++],
              *encn_g  = (const float*)d_in[i++], *encn_be = (const float*)d_in[i++];
  const float *ence_W0 = (const float*)d_in[i++], *ence_b0 = (const float*)d_in[i++],
              *ence_W1 = (const float*)d_in[i++], *ence_b1 = (const float*)d_in[i++],
              *ence_W2 = (const float*)d_in[i++], *ence_b2 = (const float*)d_in[i++],
              *ence_g  = (const float*)d_in[i++], *ence_be = (const float*)d_in[i++];
  const float *msg_W0 = (const float*)d_in[i++], *msg_b0 = (const float*)d_in[i++],
              *msg_W1 = (const float*)d_in[i++], *msg_b1 = (const float*)d_in[i++],
              *msg_W2 = (const float*)d_in[i++], *msg_b2 = (const float*)d_in[i++],
              *msg_g  = (const float*)d_in[i++], *msg_be = (const float*)d_in[i++];
  const float *upd_W0 = (const float*)d_in[i++], *upd_b0 = (const float*)d_in[i++],
              *upd_W1 = (const float*)d_in[i++], *upd_b1 = (const float*)d_in[i++],
              *upd_W2 = (const float*)d_in[i++], *upd_b2 = (const float*)d_in[i++],
              *upd_g  = (const float*)d_in[i++], *upd_be = (const float*)d_in[i++];
  const float *dec_W0 = (const float*)d_in[i++], *dec_b0 = (const float*)d_in[i++],
              *dec_W1 = (const float*)d_in[i++], *dec_b1 = (const float*)d_in[i++],
              *dec_W2 = (const float*)d_in[i++], *dec_b2 = (const float*)d_in[i++];

  // workspace layout (~71 MB)
  char* w = (char*)d_ws;
  float* h      = (float*)w;            w += (size_t)NN * 128 * 4;
  float* pooled = (float*)w;            w += (size_t)NN * 128 * 4;
  u16*   h_bf   = (u16*)w;              w += (size_t)NN * 128 * 2;
  u16*   e_bf   = (u16*)w;              w += (size_t)EE * 128 * 2;
  u16*   m_buf  = (u16*)w;              w += (size_t)EE * 128 * 2;
  u16*   Wt0    = (u16*)w;              w += (size_t)10 * 128 * 384 * 2;
  u16*   Wt1    = (u16*)w;              w += (size_t)10 * 128 * 128 * 2;
  u16*   Wt2    = (u16*)w;              w += (size_t)10 * 128 * 128 * 2;
  int*   cnt    = (int*)w;              w += (size_t)NN * 4;
  int*   offs   = (int*)w;              w += (size_t)(NN + 1) * 4;
  int*   curs   = (int*)w;              w += (size_t)NN * 4;
  int*   sortp  = (int*)w;              w += (size_t)EE * 4;

  const int NB_N = (NN + 31) / 32;   // 313
  const int NB_E32 = EE / 32;        // 2500
  const int NB_E128 = EE / 128;      // 625
  const int NB_E256 = (EE + 255) / 256;

  // CSR build (once per launch)
  hipMemsetAsync(cnt, 0, (size_t)NN * 4, stream);
  hist_k<<<NB_E256, 256, 0, stream>>>(receivers, cnt);
  scan_k<<<1, 1024, 0, stream>>>(cnt, offs, curs);
  scatter_k<<<NB_E256, 256, 0, stream>>>(receivers, curs, sortp);

  // weight pre-transpose (bf16 W^T)
  wtrans_k<<<10 * (384 / 32) * 4, 256, 0, stream>>>(msg_W0, Wt0, 384);
  wtrans_k<<<10 * (128 / 32) * 4, 256, 0, stream>>>(msg_W1, Wt1, 128);
  wtrans_k<<<10 * (128 / 32) * 4, 256, 0, stream>>>(msg_W2, Wt2, 128);

  enc_node_k<<<NB_N, 256, 0, stream>>>(node_feat, encn_W0, encn_b0, encn_W1, encn_b1,
                                       encn_W2, encn_b2, encn_g, encn_be, h, h_bf);
  enc_edge_k<<<NB_E32, 256, 0, stream>>>(edge_feat, ence_W0, ence_b0, ence_W1, ence_b1,
                                         ence_W2, ence_b2, ence_g, ence_be, e_bf);
  for (int t = 0; t < TT; ++t) {
    msg_mfma_k<<<NB_E128, 256, 0, stream>>>(h_bf, e_bf, senders, receivers, sortp,
        Wt0 + (size_t)t * 128 * 384, msg_b0 + (size_t)t * 128,
        Wt1 + (size_t)t * 128 * 128, msg_b1 + (size_t)t * 128,
        Wt2 + (size_t)t * 128 * 128, msg_b2 + (size_t)t * 128,
        msg_g + (size_t)t * 128, msg_be + (size_t)t * 128, m_buf);
    pool_k<<<NN / 4, 256, 0, stream>>>(m_buf, offs, pooled);
    upd_k<<<NB_N, 256, 0, stream>>>(h, pooled,
        upd_W0 + (size_t)t * 256 * 128, upd_b0 + (size_t)t * 128,
        upd_W1 + (size_t)t * 128 * 128, upd_b1 + (size_t)t * 128,
        upd_W2 + (size_t)t * 128 * 128, upd_b2 + (size_t)t * 128,
        upd_g + (size_t)t * 128, upd_be + (size_t)t * 128, h_bf);
  }
  dec_k<<<NB_N, 256, 0, stream>>>(h, dec_W0, dec_b0, dec_W1, dec_b1, dec_W2, dec_b2,
                                  (float*)d_out);
}

// Round 4
// 826.433 us; speedup vs baseline: 4.2327x; 1.2291x over previous
//
#include <hip/hip_runtime.h>

#define NN 10000
#define EE 80000
#define TT 10

typedef unsigned short u16;
typedef unsigned int u32;
using f32x4  = __attribute__((ext_vector_type(4))) float;
using bf16x8 = __attribute__((ext_vector_type(8))) short;

__device__ __forceinline__ u16 f2bf(float f) {
  union { float f; u32 u; } v; v.f = f;
  return (u16)((v.u + 0x7fffu + ((v.u >> 16) & 1u)) >> 16);   // RNE
}
__device__ __forceinline__ u32 pk2(float lo, float hi) {
  return (u32)f2bf(lo) | ((u32)f2bf(hi) << 16);
}
__device__ __forceinline__ float bflo(u32 v) { union { u32 u; float f; } x; x.u = v << 16; return x.f; }
__device__ __forceinline__ float bfhi(u32 v) { union { u32 u; float f; } x; x.u = v & 0xffff0000u; return x.f; }

// ===========================================================================
// fp32 helpers (dec only)
// ===========================================================================

__device__ __forceinline__ void initacc(const float* __restrict__ b, int tid, float acc[4][4]) {
  const int j0 = (tid & 31) * 4;
  float4 b4 = *(const float4*)(b + j0);
  #pragma unroll
  for (int rr = 0; rr < 4; ++rr) {
    acc[rr][0] = b4.x; acc[rr][1] = b4.y; acc[rr][2] = b4.z; acc[rr][3] = b4.w;
  }
}

template<int K, int SX, bool RELU>
__device__ __forceinline__ void gemm32(const float* __restrict__ W,
                                       const float* __restrict__ b,
                                       const float* __restrict__ xs,
                                       float acc[4][4], int tid) {
  const int j0 = (tid & 31) * 4;
  const int r0 = (tid >> 5) * 4;
  initacc(b, tid, acc);
  #pragma unroll 2
  for (int k = 0; k < K; k += 4) {
    float4 x[4];
    #pragma unroll
    for (int rr = 0; rr < 4; ++rr) x[rr] = *(const float4*)(xs + (r0 + rr) * SX + k);
    #pragma unroll
    for (int kk = 0; kk < 4; ++kk) {
      float4 w = *(const float4*)(W + (size_t)(k + kk) * 128 + j0);
      #pragma unroll
      for (int rr = 0; rr < 4; ++rr) {
        float xv = (kk == 0) ? x[rr].x : (kk == 1) ? x[rr].y : (kk == 2) ? x[rr].z : x[rr].w;
        acc[rr][0] = fmaf(xv, w.x, acc[rr][0]);
        acc[rr][1] = fmaf(xv, w.y, acc[rr][1]);
        acc[rr][2] = fmaf(xv, w.z, acc[rr][2]);
        acc[rr][3] = fmaf(xv, w.w, acc[rr][3]);
      }
    }
  }
  if (RELU) {
    #pragma unroll
    for (int rr = 0; rr < 4; ++rr)
      #pragma unroll
      for (int c = 0; c < 4; ++c)
        acc[rr][c] = acc[rr][c] > 0.f ? acc[rr][c] : 0.f;
  }
}

__device__ __forceinline__ void store32(const float acc[4][4], float* out, int tid) {
  const int j0 = (tid & 31) * 4;
  const int r0 = (tid >> 5) * 4;
  #pragma unroll
  for (int rr = 0; rr < 4; ++rr) {
    float4 v = {acc[rr][0], acc[rr][1], acc[rr][2], acc[rr][3]};
    *(float4*)(out + (r0 + rr) * 128 + j0) = v;
  }
}

// decoder: h -> MLP(128->128->128->3) -> out  (fp32)
__global__ __launch_bounds__(256) void dec_k(
    const float* __restrict__ h,
    const float* __restrict__ W0, const float* __restrict__ b0,
    const float* __restrict__ W1, const float* __restrict__ b1,
    const float* __restrict__ W2, const float* __restrict__ b2,
    float* __restrict__ out) {
  __shared__ float xs[32 * 128];
  __shared__ float hb0[32 * 128];
  float* hb1 = xs;
  const int tid = threadIdx.x;
  const int row0 = blockIdx.x * 32;
  for (int q = tid; q < 32 * 32; q += 256) {
    int r = q >> 5, c = q & 31;
    int gn = row0 + r;
    float4 v = {0.f, 0.f, 0.f, 0.f};
    if (gn < NN) v = *(const float4*)(h + (size_t)gn * 128 + c * 4);
    *(float4*)(xs + r * 128 + c * 4) = v;
  }
  __syncthreads();
  float acc[4][4];
  gemm32<128, 128, true>(W0, b0, xs, acc, tid);  store32(acc, hb0, tid); __syncthreads();
  gemm32<128, 128, true>(W1, b1, hb0, acc, tid); store32(acc, hb1, tid); __syncthreads();
  if (tid < 96) {
    int r = tid / 3, o = tid - (tid / 3) * 3;
    int gn = row0 + r;
    float a = b2[o];
    for (int k = 0; k < 128; ++k) a = fmaf(hb1[r * 128 + k], W2[k * 3 + o], a);
    if (gn < NN) out[(size_t)gn * 3 + o] = a;
  }
}

// ===========================================================================
// CSR build (per-launch; deterministic work)
// ===========================================================================

__global__ __launch_bounds__(256) void hist_k(const int* __restrict__ rcv, int* __restrict__ cnt) {
  int e = blockIdx.x * 256 + threadIdx.x;
  if (e < EE) atomicAdd(&cnt[rcv[e]], 1);
}

__global__ __launch_bounds__(1024) void scan_k(const int* __restrict__ cnt,
                                               int* __restrict__ offs, int* __restrict__ curs) {
  __shared__ int ps[1024];
  const int t = threadIdx.x;
  int loc[10], s = 0;
  #pragma unroll
  for (int j = 0; j < 10; ++j) {
    int idx = t * 10 + j;
    int v = (idx < NN) ? cnt[idx] : 0;
    loc[j] = s; s += v;
  }
  ps[t] = s;
  __syncthreads();
  for (int off = 1; off < 1024; off <<= 1) {
    int v = (t >= off) ? ps[t - off] : 0;
    __syncthreads();
    ps[t] += v;
    __syncthreads();
  }
  int pre = (t == 0) ? 0 : ps[t - 1];
  #pragma unroll
  for (int j = 0; j < 10; ++j) {
    int idx = t * 10 + j;
    if (idx < NN) { int o = pre + loc[j]; offs[idx] = o; curs[idx] = o; }
  }
  if (t == 1023) offs[NN] = ps[1023];
}

__global__ __launch_bounds__(256) void scatter_k(const int* __restrict__ rcv,
                                                 int* __restrict__ curs, int* __restrict__ sortpos) {
  int e = blockIdx.x * 256 + threadIdx.x;
  if (e < EE) sortpos[e] = atomicAdd(&curs[rcv[e]], 1);
}

// segment-sum: one wave per node; m_buf rows are receiver-sorted -> contiguous
__global__ __launch_bounds__(256) void pool_k(const u16* __restrict__ m,
                                              const int* __restrict__ offs,
                                              float* __restrict__ pooled) {
  const int lane = threadIdx.x & 63;
  const int n = blockIdx.x * 4 + (threadIdx.x >> 6);
  const int j0 = offs[n], j1 = offs[n + 1];
  float a0 = 0.f, a1 = 0.f;
  int j = j0;
  for (; j + 4 <= j1; j += 4) {
    u32 v0 = *(const u32*)(m + (size_t)(j + 0) * 128 + lane * 2);
    u32 v1 = *(const u32*)(m + (size_t)(j + 1) * 128 + lane * 2);
    u32 v2 = *(const u32*)(m + (size_t)(j + 2) * 128 + lane * 2);
    u32 v3 = *(const u32*)(m + (size_t)(j + 3) * 128 + lane * 2);
    a0 += bflo(v0) + bflo(v1) + bflo(v2) + bflo(v3);
    a1 += bfhi(v0) + bfhi(v1) + bfhi(v2) + bfhi(v3);
  }
  for (; j < j1; ++j) {
    u32 v = *(const u32*)(m + (size_t)j * 128 + lane * 2);
    a0 += bflo(v); a1 += bfhi(v);
  }
  float2 o = {a0, a1};
  *(float2*)(pooled + (size_t)n * 128 + lane * 2) = o;
}

// ===========================================================================
// weight pre-transpose: dst[t][n][k] = bf16(src[t][k][n]) (K mult of 32)
// ===========================================================================
__global__ __launch_bounds__(256) void wtrans_k(const float* __restrict__ src,
                                                u16* __restrict__ dst, int K) {
  __shared__ float tile[32][33];
  const int tiles_per_t = (K / 32) * 4;
  const int t  = blockIdx.x / tiles_per_t;
  const int rem = blockIdx.x - t * tiles_per_t;
  const int kt = rem >> 2, nt = rem & 3;
  const float* s = src + (size_t)t * K * 128;
  u16* d = dst + (size_t)t * 128 * K;
  const int r = threadIdx.x >> 5, c = threadIdx.x & 31;
  for (int rr = r; rr < 32; rr += 8)
    tile[rr][c] = s[(size_t)(kt * 32 + rr) * 128 + nt * 32 + c];
  __syncthreads();
  for (int rr = r; rr < 32; rr += 8)
    d[(size_t)(nt * 32 + rr) * K + kt * 32 + c] = f2bf(tile[c][rr]);
}

// small-K pad transpose: dst[n][k<64] = k<K ? bf16(src[k][n]) : 0   (1 block)
__global__ __launch_bounds__(128) void wtrans_pad_k(const float* __restrict__ src,
                                                    u16* __restrict__ dst, int K) {
  const int ch = threadIdx.x;
  for (int k = 0; k < 64; ++k)
    dst[ch * 64 + k] = (k < K) ? f2bf(src[(size_t)k * 128 + ch]) : (u16)0;
}

// ===========================================================================
// unified MFMA MLP3(+LN) kernel: 128 rows x 128 ch per block, BK=64
//   MODE 0 = msg   (gather h/h/e,       out m_buf[sortpos])
//   MODE 1 = upd   (gather h_bf|pooled, residual, out h + h_bf)
//   MODE 2 = encn  (gather node_feat,   out h + h_bf)
//   MODE 3 = ence  (gather edge_feat,   out e_bf)
// ===========================================================================
template<int MODE, int KT0>
__global__ __launch_bounds__(256, 2) void mlp3_mfma_k(
    const u16* __restrict__ h_bf, const u16* __restrict__ e_bf,
    const float* __restrict__ h32, const float* __restrict__ pooled,
    const float* __restrict__ feat,
    const int* __restrict__ snd, const int* __restrict__ rcv,
    const int* __restrict__ sortpos,
    const u16* __restrict__ Wt0, const float* __restrict__ b0,
    const u16* __restrict__ Wt1, const float* __restrict__ b1,
    const u16* __restrict__ Wt2, const float* __restrict__ b2,
    const float* __restrict__ g,  const float* __restrict__ be,
    u16* __restrict__ m_out, float* __restrict__ h_out, u16* __restrict__ hbf_out) {
  constexpr int K0 = KT0 * 64;
  __shared__ u16 XS[2][128 * 64];
  __shared__ u16 WS[2][128 * 64];
  __shared__ float part_s[2][128], part_q[2][128];
  __shared__ int ir[128], is[128], sp[128];

  const int tid = threadIdx.x;
  const int lane = tid & 63;
  const int wq = tid >> 6;
  const int wm = wq >> 1, wn = wq & 1;
  const int l15 = lane & 15, lq = lane >> 4;
  const int row0 = blockIdx.x * 128;
  const int lr = lane >> 3;
  const int cj = lane & 7;

  if constexpr (MODE == 0) {
    if (tid < 128) {
      ir[tid] = rcv[row0 + tid];
      is[tid] = snd[row0 + tid];
      sp[tid] = sortpos[row0 + tid];
    }
    __syncthreads();
  }

  auto load_x = [&](int kt, uint4 v[4]) {
    #pragma unroll
    for (int i = 0; i < 4; ++i) {
      int q = wq * 32 + i * 8 + lr;
      if constexpr (MODE == 0) {
        const u16* base;
        if (kt < 2)      base = h_bf + (size_t)ir[q] * 128;
        else if (kt < 4) base = h_bf + (size_t)is[q] * 128;
        else             base = e_bf + (size_t)(row0 + q) * 128;
        v[i] = *(const uint4*)(base + (kt & 1) * 64 + cj * 8);
      } else if constexpr (MODE == 1) {
        int gn = row0 + q;
        if (gn < NN) {
          if (kt < 2) {
            v[i] = *(const uint4*)(h_bf + (size_t)gn * 128 + kt * 64 + cj * 8);
          } else {
            const float* p = pooled + (size_t)gn * 128 + (kt - 2) * 64 + cj * 8;
            float4 a = *(const float4*)p;
            float4 b = *(const float4*)(p + 4);
            v[i].x = pk2(a.x, a.y); v[i].y = pk2(a.z, a.w);
            v[i].z = pk2(b.x, b.y); v[i].w = pk2(b.z, b.w);
          }
        } else v[i] = make_uint4(0, 0, 0, 0);
      } else if constexpr (MODE == 2) {
        int gn = row0 + q;
        float x[8];
        #pragma unroll
        for (int j = 0; j < 8; ++j) {
          int k = cj * 8 + j;
          x[j] = (gn < NN && k < 30) ? feat[(size_t)gn * 30 + k] : 0.f;
        }
        v[i].x = pk2(x[0], x[1]); v[i].y = pk2(x[2], x[3]);
        v[i].z = pk2(x[4], x[5]); v[i].w = pk2(x[6], x[7]);
      } else {
        int ge = row0 + q;
        float x[8];
        #pragma unroll
        for (int j = 0; j < 8; ++j) {
          int k = cj * 8 + j;
          x[j] = (k < 3) ? feat[(size_t)ge * 3 + k] : 0.f;
        }
        v[i].x = pk2(x[0], x[1]); v[i].y = pk2(x[2], x[3]);
        v[i].z = pk2(x[4], x[5]); v[i].w = pk2(x[6], x[7]);
      }
    }
  };
  auto load_w = [&](const u16* Wt, int kstr, int kt, uint4 v[4]) {
    #pragma unroll
    for (int i = 0; i < 4; ++i) {
      int ch = wq * 32 + i * 8 + lr;
      v[i] = *(const uint4*)(Wt + (size_t)ch * kstr + kt * 64 + cj * 8);
    }
  };
  auto stage = [&](u16 (*B)[128 * 64], int buf, const uint4 v[4]) {
    #pragma unroll
    for (int i = 0; i < 4; ++i) {
      int q = wq * 32 + i * 8 + lr;
      int c = cj ^ (lr & 7);
      *(uint4*)&B[buf][q * 64 + c * 8] = v[i];
    }
  };

  f32x4 acc[4][4];
  auto init_bias = [&](const float* b) {
    f32x4 bv[4];
    #pragma unroll
    for (int ct = 0; ct < 4; ++ct) bv[ct] = *(const f32x4*)(b + wm * 64 + ct * 16 + lq * 4);
    #pragma unroll
    for (int ct = 0; ct < 4; ++ct)
      #pragma unroll
      for (int et = 0; et < 4; ++et) acc[ct][et] = bv[ct];
  };
  auto compute_tile = [&](const u16* xbuf, const u16* wbuf) {
    #pragma unroll
    for (int k0 = 0; k0 < 2; ++k0) {
      bf16x8 wf[4], xf[4];
      #pragma unroll
      for (int ct = 0; ct < 4; ++ct) {
        int ch = wm * 64 + ct * 16 + l15;
        wf[ct] = *(const bf16x8*)&wbuf[ch * 64 + (((k0 * 4 + lq) ^ (l15 & 7)) * 8)];
      }
      #pragma unroll
      for (int et = 0; et < 4; ++et) {
        int ed = wn * 64 + et * 16 + l15;
        xf[et] = *(const bf16x8*)&xbuf[ed * 64 + (((k0 * 4 + lq) ^ (l15 & 7)) * 8)];
      }
      #pragma unroll
      for (int ct = 0; ct < 4; ++ct)
        #pragma unroll
        for (int et = 0; et < 4; ++et)
          acc[ct][et] = __builtin_amdgcn_mfma_f32_16x16x32_bf16(wf[ct], xf[et], acc[ct][et], 0, 0, 0);
    }
  };
  auto store_h = [&](bool relu) {
    #pragma unroll
    for (int ct = 0; ct < 4; ++ct)
      #pragma unroll
      for (int et = 0; et < 4; ++et) {
        float v0 = acc[ct][et][0], v1 = acc[ct][et][1], v2 = acc[ct][et][2], v3 = acc[ct][et][3];
        if (relu) { v0 = fmaxf(v0, 0.f); v1 = fmaxf(v1, 0.f); v2 = fmaxf(v2, 0.f); v3 = fmaxf(v3, 0.f); }
        ushort4 o = {f2bf(v0), f2bf(v1), f2bf(v2), f2bf(v3)};
        int ed = wn * 64 + et * 16 + l15;
        int c3 = ct * 2 + (lq >> 1);
        int cs = c3 ^ (l15 & 7);
        *(ushort4*)&XS[wm][ed * 64 + cs * 8 + (lq & 1) * 4] = o;
      }
  };

  uint4 vx[4], vw[4];

  // ---------------- layer 0: K0, KT0 k-tiles ----------------
  init_bias(b0);
  load_x(0, vx); load_w(Wt0, K0, 0, vw);
  stage(XS, 0, vx); stage(WS, 0, vw);
  __syncthreads();
  for (int kt = 0; kt < KT0; ++kt) {
    int cur = kt & 1, nxt = cur ^ 1;
    if (kt < KT0 - 1) { load_x(kt + 1, vx); load_w(Wt0, K0, kt + 1, vw); }
    compute_tile(XS[cur], WS[cur]);
    if (kt < KT0 - 1) { stage(XS, nxt, vx); stage(WS, nxt, vw); }
    __syncthreads();
  }
  store_h(true);          // h1 -> XS[0..1]
  __syncthreads();

  // ---------------- layer 1: K=128, 2 k-tiles ----------------
  init_bias(b1);
  load_w(Wt1, 128, 0, vw); stage(WS, 0, vw);
  __syncthreads();
  for (int kt = 0; kt < 2; ++kt) {
    if (kt < 1) load_w(Wt1, 128, 1, vw);
    compute_tile(XS[kt], WS[kt]);
    if (kt < 1) stage(WS, 1, vw);
    __syncthreads();
  }
  store_h(true);          // h2 -> XS[0..1]
  __syncthreads();

  // ---------------- layer 2: K=128, 2 k-tiles ----------------
  init_bias(b2);
  load_w(Wt2, 128, 0, vw); stage(WS, 0, vw);
  __syncthreads();
  for (int kt = 0; kt < 2; ++kt) {
    if (kt < 1) load_w(Wt2, 128, 1, vw);
    compute_tile(XS[kt], WS[kt]);
    if (kt < 1) stage(WS, 1, vw);
    __syncthreads();
  }

  // ---------------- LayerNorm (fp32, cross-wave over wm halves) ----------------
  float ss[4], qs[4];
  #pragma unroll
  for (int et = 0; et < 4; ++et) {
    float s = 0.f, q = 0.f;
    #pragma unroll
    for (int ct = 0; ct < 4; ++ct)
      #pragma unroll
      for (int i = 0; i < 4; ++i) { float v = acc[ct][et][i]; s += v; q += v * v; }
    s += __shfl_xor(s, 16, 64); s += __shfl_xor(s, 32, 64);
    q += __shfl_xor(q, 16, 64); q += __shfl_xor(q, 32, 64);
    ss[et] = s; qs[et] = q;
  }
  if (lane < 16) {
    #pragma unroll
    for (int et = 0; et < 4; ++et) {
      part_s[wm][wn * 64 + et * 16 + lane] = ss[et];
      part_q[wm][wn * 64 + et * 16 + lane] = qs[et];
    }
  }
  __syncthreads();
  float mean[4], inv[4];
  #pragma unroll
  for (int et = 0; et < 4; ++et) {
    int ed = wn * 64 + et * 16 + l15;
    float S = part_s[0][ed] + part_s[1][ed];
    float Q = part_q[0][ed] + part_q[1][ed];
    float m = S * (1.f / 128.f);
    float var = Q * (1.f / 128.f) - m * m;
    mean[et] = m; inv[et] = rsqrtf(var + 1e-3f);
  }
  #pragma unroll
  for (int ct = 0; ct < 4; ++ct) {
    f32x4 g4 = *(const f32x4*)(g  + wm * 64 + ct * 16 + lq * 4);
    f32x4 b4 = *(const f32x4*)(be + wm * 64 + ct * 16 + lq * 4);
    #pragma unroll
    for (int et = 0; et < 4; ++et)
      #pragma unroll
      for (int i = 0; i < 4; ++i)
        acc[ct][et][i] = g4[i] * (acc[ct][et][i] - mean[et]) * inv[et] + b4[i];
  }

  if constexpr (MODE == 0) {
    store_h(false);
    __syncthreads();
    int ed = tid >> 1, hf = tid & 1;
    size_t drow = (size_t)sp[ed] * 128;
    #pragma unroll
    for (int c = hf * 8; c < hf * 8 + 8; ++c) {
      int buf = c >> 3, c3 = c & 7, cs = c3 ^ (ed & 7);
      uint4 v = *(const uint4*)&XS[buf][ed * 64 + cs * 8];
      *(uint4*)(m_out + drow + c * 8) = v;
    }
  } else {
    const int ch0 = wm * 64 + lq * 4;
    #pragma unroll
    for (int ct = 0; ct < 4; ++ct)
      #pragma unroll
      for (int et = 0; et < 4; ++et) {
        int row = wn * 64 + et * 16 + l15;
        int gr = row0 + row;
        if (MODE == 3 || gr < NN) {
          f32x4 v = acc[ct][et];
          if constexpr (MODE == 1) {
            f32x4 old = *(const f32x4*)(h32 + (size_t)gr * 128 + ch0 + ct * 16);
            v = v + old;
          }
          ushort4 o = {f2bf(v[0]), f2bf(v[1]), f2bf(v[2]), f2bf(v[3])};
          if constexpr (MODE != 3)
            *(f32x4*)(h_out + (size_t)gr * 128 + ch0 + ct * 16) = v;
          *(ushort4*)(hbf_out + (size_t)gr * 128 + ch0 + ct * 16) = o;
        }
      }
  }
}

// ===========================================================================
extern "C" void kernel_launch(void* const* d_in, const int* in_sizes, int n_in,
                              void* d_out, int out_size, void* d_ws, size_t ws_size,
                              hipStream_t stream) {
  int i = 0;
  const float* node_feat = (const float*)d_in[i++];
  const float* edge_feat = (const float*)d_in[i++];
  const int*   senders   = (const int*)d_in[i++];
  const int*   receivers = (const int*)d_in[i++];
  const float *encn_W0 = (const float*)d_in[i++], *encn_b0 = (const float*)d_in[i++],
              *encn_W1 = (const float*)d_in[i++], *encn_b1 = (const float*)d_in[i++],
              *encn_W2 = (const float*)d_in[i++], *encn_b2 = (const float*)d_in[i++],
              *encn_g  = (const float*)d_in[i++], *encn_be = (const float*)d_in[i++];
  const float *ence_W0 = (const float*)d_in[i++], *ence_b0 = (const float*)d_in[i++],
              *ence_W1 = (const float*)d_in[i++], *ence_b1 = (const float*)d_in[i++],
              *ence_W2 = (const float*)d_in[i++], *ence_b2 = (const float*)d_in[i++],
              *ence_g  = (const float*)d_in[i++], *ence_be = (const float*)d_in[i++];
  const float *msg_W0 = (const float*)d_in[i++], *msg_b0 = (const float*)d_in[i++],
              *msg_W1 = (const float*)d_in[i++], *msg_b1 = (const float*)d_in[i++],
              *msg_W2 = (const float*)d_in[i++], *msg_b2 = (const float*)d_in[i++],
              *msg_g  = (const float*)d_in[i++], *msg_be = (const float*)d_in[i++];
  const float *upd_W0 = (const float*)d_in[i++], *upd_b0 = (const float*)d_in[i++],
              *upd_W1 = (const float*)d_in[i++], *upd_b1 = (const float*)d_in[i++],
              *upd_W2 = (const float*)d_in[i++], *upd_b2 = (const float*)d_in[i++],
              *upd_g  = (const float*)d_in[i++], *upd_be = (const float*)d_in[i++];
  const float *dec_W0 = (const float*)d_in[i++], *dec_b0 = (const float*)d_in[i++],
              *dec_W1 = (const float*)d_in[i++], *dec_b1 = (const float*)d_in[i++],
              *dec_W2 = (const float*)d_in[i++], *dec_b2 = (const float*)d_in[i++];

  // workspace layout (~58 MB)
  char* w = (char*)d_ws;
  float* h      = (float*)w;            w += (size_t)NN * 128 * 4;
  float* pooled = (float*)w;            w += (size_t)NN * 128 * 4;
  u16*   h_bf   = (u16*)w;              w += (size_t)NN * 128 * 2;
  u16*   e_bf   = (u16*)w;              w += (size_t)EE * 128 * 2;
  u16*   m_buf  = (u16*)w;              w += (size_t)EE * 128 * 2;
  u16*   mWt0   = (u16*)w;              w += (size_t)10 * 128 * 384 * 2;
  u16*   mWt1   = (u16*)w;              w += (size_t)10 * 128 * 128 * 2;
  u16*   mWt2   = (u16*)w;              w += (size_t)10 * 128 * 128 * 2;
  u16*   uWt0   = (u16*)w;              w += (size_t)10 * 128 * 256 * 2;
  u16*   uWt1   = (u16*)w;              w += (size_t)10 * 128 * 128 * 2;
  u16*   uWt2   = (u16*)w;              w += (size_t)10 * 128 * 128 * 2;
  u16*   nWt0   = (u16*)w;              w += (size_t)128 * 64 * 2;
  u16*   nWt1   = (u16*)w;              w += (size_t)128 * 128 * 2;
  u16*   nWt2   = (u16*)w;              w += (size_t)128 * 128 * 2;
  u16*   eWt0   = (u16*)w;              w += (size_t)128 * 64 * 2;
  u16*   eWt1   = (u16*)w;              w += (size_t)128 * 128 * 2;
  u16*   eWt2   = (u16*)w;              w += (size_t)128 * 128 * 2;
  int*   cnt    = (int*)w;              w += (size_t)NN * 4;
  int*   offs   = (int*)w;              w += (size_t)(NN + 1) * 4;
  int*   curs   = (int*)w;              w += (size_t)NN * 4;
  int*   sortp  = (int*)w;              w += (size_t)EE * 4;

  const int NB_N128 = (NN + 127) / 128;  // 79
  const int NB_E128 = EE / 128;          // 625
  const int NB_E256 = (EE + 255) / 256;

  // CSR build (once per launch)
  hipMemsetAsync(cnt, 0, (size_t)NN * 4, stream);
  hist_k<<<NB_E256, 256, 0, stream>>>(receivers, cnt);
  scan_k<<<1, 1024, 0, stream>>>(cnt, offs, curs);
  scatter_k<<<NB_E256, 256, 0, stream>>>(receivers, curs, sortp);

  // weight pre-transposes (bf16 W^T)
  wtrans_k<<<10 * (384 / 32) * 4, 256, 0, stream>>>(msg_W0, mWt0, 384);
  wtrans_k<<<10 * (128 / 32) * 4, 256, 0, stream>>>(msg_W1, mWt1, 128);
  wtrans_k<<<10 * (128 / 32) * 4, 256, 0, stream>>>(msg_W2, mWt2, 128);
  wtrans_k<<<10 * (256 / 32) * 4, 256, 0, stream>>>(upd_W0, uWt0, 256);
  wtrans_k<<<10 * (128 / 32) * 4, 256, 0, stream>>>(upd_W1, uWt1, 128);
  wtrans_k<<<10 * (128 / 32) * 4, 256, 0, stream>>>(upd_W2, uWt2, 128);
  wtrans_pad_k<<<1, 128, 0, stream>>>(encn_W0, nWt0, 30);
  wtrans_k<<<(128 / 32) * 4, 256, 0, stream>>>(encn_W1, nWt1, 128);
  wtrans_k<<<(128 / 32) * 4, 256, 0, stream>>>(encn_W2, nWt2, 128);
  wtrans_pad_k<<<1, 128, 0, stream>>>(ence_W0, eWt0, 3);
  wtrans_k<<<(128 / 32) * 4, 256, 0, stream>>>(ence_W1, eWt1, 128);
  wtrans_k<<<(128 / 32) * 4, 256, 0, stream>>>(ence_W2, eWt2, 128);

  // encoders (MFMA)
  mlp3_mfma_k<2, 1><<<NB_N128, 256, 0, stream>>>(
      nullptr, nullptr, nullptr, nullptr, node_feat, nullptr, nullptr, nullptr,
      nWt0, encn_b0, nWt1, encn_b1, nWt2, encn_b2, encn_g, encn_be,
      nullptr, h, h_bf);
  mlp3_mfma_k<3, 1><<<NB_E128, 256, 0, stream>>>(
      nullptr, nullptr, nullptr, nullptr, edge_feat, nullptr, nullptr, nullptr,
      eWt0, ence_b0, eWt1, ence_b1, eWt2, ence_b2, ence_g, ence_be,
      nullptr, nullptr, e_bf);

  for (int t = 0; t < TT; ++t) {
    mlp3_mfma_k<0, 6><<<NB_E128, 256, 0, stream>>>(
        h_bf, e_bf, nullptr, nullptr, nullptr, senders, receivers, sortp,
        mWt0 + (size_t)t * 128 * 384, msg_b0 + (size_t)t * 128,
        mWt1 + (size_t)t * 128 * 128, msg_b1 + (size_t)t * 128,
        mWt2 + (size_t)t * 128 * 128, msg_b2 + (size_t)t * 128,
        msg_g + (size_t)t * 128, msg_be + (size_t)t * 128,
        m_buf, nullptr, nullptr);
    pool_k<<<NN / 4, 256, 0, stream>>>(m_buf, offs, pooled);
    mlp3_mfma_k<1, 4><<<NB_N128, 256, 0, stream>>>(
        h_bf, nullptr, h, pooled, nullptr, nullptr, nullptr, nullptr,
        uWt0 + (size_t)t * 128 * 256, upd_b0 + (size_t)t * 128,
        uWt1 + (size_t)t * 128 * 128, upd_b1 + (size_t)t * 128,
        uWt2 + (size_t)t * 128 * 128, upd_b2 + (size_t)t * 128,
        upd_g + (size_t)t * 128, upd_be + (size_t)t * 128,
        nullptr, h, h_bf);
  }
  dec_k<<<(NN + 31) / 32, 256, 0, stream>>>(h, dec_W0, dec_b0, dec_W1, dec_b1,
                                            dec_W2, dec_b2, (float*)d_out);
}

// Round 5
// 825.690 us; speedup vs baseline: 4.2366x; 1.0009x over previous
//
#include <hip/hip_runtime.h>

#define NN 10000
#define EE 80000
#define TT 10

typedef unsigned short u16;
typedef unsigned int u32;
using f32x4  = __attribute__((ext_vector_type(4))) float;
using bf16x8 = __attribute__((ext_vector_type(8))) short;

__device__ __forceinline__ u16 f2bf(float f) {
  union { float f; u32 u; } v; v.f = f;
  return (u16)((v.u + 0x7fffu + ((v.u >> 16) & 1u)) >> 16);   // RNE
}
__device__ __forceinline__ u32 pk2(float lo, float hi) {
  return (u32)f2bf(lo) | ((u32)f2bf(hi) << 16);
}
__device__ __forceinline__ float bflo(u32 v) { union { u32 u; float f; } x; x.u = v << 16; return x.f; }
__device__ __forceinline__ float bfhi(u32 v) { union { u32 u; float f; } x; x.u = v & 0xffff0000u; return x.f; }

// ===========================================================================
// fp32 helpers (dec only)
// ===========================================================================

__device__ __forceinline__ void initacc(const float* __restrict__ b, int tid, float acc[4][4]) {
  const int j0 = (tid & 31) * 4;
  float4 b4 = *(const float4*)(b + j0);
  #pragma unroll
  for (int rr = 0; rr < 4; ++rr) {
    acc[rr][0] = b4.x; acc[rr][1] = b4.y; acc[rr][2] = b4.z; acc[rr][3] = b4.w;
  }
}

template<int K, int SX, bool RELU>
__device__ __forceinline__ void gemm32(const float* __restrict__ W,
                                       const float* __restrict__ b,
                                       const float* __restrict__ xs,
                                       float acc[4][4], int tid) {
  const int j0 = (tid & 31) * 4;
  const int r0 = (tid >> 5) * 4;
  initacc(b, tid, acc);
  #pragma unroll 2
  for (int k = 0; k < K; k += 4) {
    float4 x[4];
    #pragma unroll
    for (int rr = 0; rr < 4; ++rr) x[rr] = *(const float4*)(xs + (r0 + rr) * SX + k);
    #pragma unroll
    for (int kk = 0; kk < 4; ++kk) {
      float4 w = *(const float4*)(W + (size_t)(k + kk) * 128 + j0);
      #pragma unroll
      for (int rr = 0; rr < 4; ++rr) {
        float xv = (kk == 0) ? x[rr].x : (kk == 1) ? x[rr].y : (kk == 2) ? x[rr].z : x[rr].w;
        acc[rr][0] = fmaf(xv, w.x, acc[rr][0]);
        acc[rr][1] = fmaf(xv, w.y, acc[rr][1]);
        acc[rr][2] = fmaf(xv, w.z, acc[rr][2]);
        acc[rr][3] = fmaf(xv, w.w, acc[rr][3]);
      }
    }
  }
  if (RELU) {
    #pragma unroll
    for (int rr = 0; rr < 4; ++rr)
      #pragma unroll
      for (int c = 0; c < 4; ++c)
        acc[rr][c] = acc[rr][c] > 0.f ? acc[rr][c] : 0.f;
  }
}

__device__ __forceinline__ void store32(const float acc[4][4], float* out, int tid) {
  const int j0 = (tid & 31) * 4;
  const int r0 = (tid >> 5) * 4;
  #pragma unroll
  for (int rr = 0; rr < 4; ++rr) {
    float4 v = {acc[rr][0], acc[rr][1], acc[rr][2], acc[rr][3]};
    *(float4*)(out + (r0 + rr) * 128 + j0) = v;
  }
}

// decoder: h -> MLP(128->128->128->3) -> out  (fp32)
__global__ __launch_bounds__(256) void dec_k(
    const float* __restrict__ h,
    const float* __restrict__ W0, const float* __restrict__ b0,
    const float* __restrict__ W1, const float* __restrict__ b1,
    const float* __restrict__ W2, const float* __restrict__ b2,
    float* __restrict__ out) {
  __shared__ float xs[32 * 128];
  __shared__ float hb0[32 * 128];
  float* hb1 = xs;
  const int tid = threadIdx.x;
  const int row0 = blockIdx.x * 32;
  for (int q = tid; q < 32 * 32; q += 256) {
    int r = q >> 5, c = q & 31;
    int gn = row0 + r;
    float4 v = {0.f, 0.f, 0.f, 0.f};
    if (gn < NN) v = *(const float4*)(h + (size_t)gn * 128 + c * 4);
    *(float4*)(xs + r * 128 + c * 4) = v;
  }
  __syncthreads();
  float acc[4][4];
  gemm32<128, 128, true>(W0, b0, xs, acc, tid);  store32(acc, hb0, tid); __syncthreads();
  gemm32<128, 128, true>(W1, b1, hb0, acc, tid); store32(acc, hb1, tid); __syncthreads();
  if (tid < 96) {
    int r = tid / 3, o = tid - (tid / 3) * 3;
    int gn = row0 + r;
    float a = b2[o];
    for (int k = 0; k < 128; ++k) a = fmaf(hb1[r * 128 + k], W2[k * 3 + o], a);
    if (gn < NN) out[(size_t)gn * 3 + o] = a;
  }
}

// ===========================================================================
// CSR build (per-launch; deterministic work)
// ===========================================================================

__global__ __launch_bounds__(256) void hist_k(const int* __restrict__ rcv, int* __restrict__ cnt) {
  int e = blockIdx.x * 256 + threadIdx.x;
  if (e < EE) atomicAdd(&cnt[rcv[e]], 1);
}

__global__ __launch_bounds__(1024) void scan_k(const int* __restrict__ cnt,
                                               int* __restrict__ offs, int* __restrict__ curs) {
  __shared__ int ps[1024];
  const int t = threadIdx.x;
  int loc[10], s = 0;
  #pragma unroll
  for (int j = 0; j < 10; ++j) {
    int idx = t * 10 + j;
    int v = (idx < NN) ? cnt[idx] : 0;
    loc[j] = s; s += v;
  }
  ps[t] = s;
  __syncthreads();
  for (int off = 1; off < 1024; off <<= 1) {
    int v = (t >= off) ? ps[t - off] : 0;
    __syncthreads();
    ps[t] += v;
    __syncthreads();
  }
  int pre = (t == 0) ? 0 : ps[t - 1];
  #pragma unroll
  for (int j = 0; j < 10; ++j) {
    int idx = t * 10 + j;
    if (idx < NN) { int o = pre + loc[j]; offs[idx] = o; curs[idx] = o; }
  }
  if (t == 1023) offs[NN] = ps[1023];
}

__global__ __launch_bounds__(256) void scatter_k(const int* __restrict__ rcv,
                                                 int* __restrict__ curs, int* __restrict__ sortpos) {
  int e = blockIdx.x * 256 + threadIdx.x;
  if (e < EE) sortpos[e] = atomicAdd(&curs[rcv[e]], 1);
}

// segment-sum: one wave per node; m_buf rows are receiver-sorted -> contiguous
__global__ __launch_bounds__(256) void pool_k(const u16* __restrict__ m,
                                              const int* __restrict__ offs,
                                              float* __restrict__ pooled) {
  const int lane = threadIdx.x & 63;
  const int n = blockIdx.x * 4 + (threadIdx.x >> 6);
  const int j0 = offs[n], j1 = offs[n + 1];
  float a0 = 0.f, a1 = 0.f;
  int j = j0;
  for (; j + 4 <= j1; j += 4) {
    u32 v0 = *(const u32*)(m + (size_t)(j + 0) * 128 + lane * 2);
    u32 v1 = *(const u32*)(m + (size_t)(j + 1) * 128 + lane * 2);
    u32 v2 = *(const u32*)(m + (size_t)(j + 2) * 128 + lane * 2);
    u32 v3 = *(const u32*)(m + (size_t)(j + 3) * 128 + lane * 2);
    a0 += bflo(v0) + bflo(v1) + bflo(v2) + bflo(v3);
    a1 += bfhi(v0) + bfhi(v1) + bfhi(v2) + bfhi(v3);
  }
  for (; j < j1; ++j) {
    u32 v = *(const u32*)(m + (size_t)j * 128 + lane * 2);
    a0 += bflo(v); a1 += bfhi(v);
  }
  float2 o = {a0, a1};
  *(float2*)(pooled + (size_t)n * 128 + lane * 2) = o;
}

// ===========================================================================
// weight pre-transpose: dst[t][n][k] = bf16(src[t*tstr + k*128 + n])
// ===========================================================================
__global__ __launch_bounds__(256) void wtrans_k(const float* __restrict__ src,
                                                u16* __restrict__ dst, int K, long tstr) {
  __shared__ float tile[32][33];
  const int tiles_per_t = (K / 32) * 4;
  const int t  = blockIdx.x / tiles_per_t;
  const int rem = blockIdx.x - t * tiles_per_t;
  const int kt = rem >> 2, nt = rem & 3;
  const float* s = src + (size_t)t * tstr;
  u16* d = dst + (size_t)t * 128 * K;
  const int r = threadIdx.x >> 5, c = threadIdx.x & 31;
  for (int rr = r; rr < 32; rr += 8)
    tile[rr][c] = s[(size_t)(kt * 32 + rr) * 128 + nt * 32 + c];
  __syncthreads();
  for (int rr = r; rr < 32; rr += 8)
    d[(size_t)(nt * 32 + rr) * K + kt * 32 + c] = f2bf(tile[c][rr]);
}

// small-K pad transpose: dst[n][k<64] = k<K ? bf16(src[k][n]) : 0   (1 block)
__global__ __launch_bounds__(128) void wtrans_pad_k(const float* __restrict__ src,
                                                    u16* __restrict__ dst, int K) {
  const int ch = threadIdx.x;
  for (int k = 0; k < 64; ++k)
    dst[ch * 64 + k] = (k < K) ? f2bf(src[(size_t)k * 128 + ch]) : (u16)0;
}

// ===========================================================================
// unified MFMA MLP3(+LN) kernel: BM rows x 128 ch per block, BK=64
//   MODE 0 = msg   (stage e seq, L0=e@W0e, +Ur[rcv]+Us[snd], out m_buf[sortpos])
//   MODE 1 = upd   (stage h_bf|pooled, residual, out h+h_bf, optional U-emit)
//   MODE 2 = encn  (stage node_feat, out h+h_bf, optional U-emit)
//   MODE 3 = ence  (stage edge_feat, out e_bf)
// U-emit (MODE 1/2, Wtr!=null): Ur = h_new@Wtr^T + b0n; Us = h_new@Wts^T  (fp32)
// ===========================================================================
template<int MODE, int KT0, int BM>
__global__ __launch_bounds__(256, 2) void mlp3_mfma_k(
    const u16* __restrict__ h_bf, const u16* __restrict__ e_bf,
    const float* __restrict__ h32, const float* __restrict__ pooled,
    const float* __restrict__ feat,
    const int* __restrict__ snd, const int* __restrict__ rcv,
    const int* __restrict__ sortpos,
    const float* __restrict__ Ur_in, const float* __restrict__ Us_in,
    const u16* __restrict__ Wt0, const float* __restrict__ b0,
    const u16* __restrict__ Wt1, const float* __restrict__ b1,
    const u16* __restrict__ Wt2, const float* __restrict__ b2,
    const float* __restrict__ g,  const float* __restrict__ be,
    const u16* __restrict__ Wtr, const u16* __restrict__ Wts,
    const float* __restrict__ b0n,
    u16* __restrict__ m_out, float* __restrict__ h_out, u16* __restrict__ hbf_out,
    float* __restrict__ Ur_out, float* __restrict__ Us_out) {
  constexpr int K0  = KT0 * 64;
  constexpr int RPW = BM / 4;     // rows staged per wave
  constexpr int NI  = RPW / 8;    // staging iterations
  constexpr int RH  = BM / 2;     // rows per wn-half
  constexpr int NET = RH / 16;    // 16-row tiles per wave

  __shared__ u16 XS[2][BM * 64];
  __shared__ u16 WS[2][128 * 64];
  __shared__ float part_s[2][BM], part_q[2][BM];
  __shared__ int ir[MODE == 0 ? 128 : 1], is[MODE == 0 ? 128 : 1], sp[MODE == 0 ? 128 : 1];

  const int tid = threadIdx.x;
  const int lane = tid & 63;
  const int wq = tid >> 6;
  const int wm = wq >> 1, wn = wq & 1;
  const int l15 = lane & 15, lq = lane >> 4;
  const int row0 = blockIdx.x * BM;
  const int lr = lane >> 3;
  const int cj = lane & 7;
  const int ch0 = wm * 64 + lq * 4;

  if constexpr (MODE == 0) {
    if (tid < 128) {
      ir[tid] = rcv[row0 + tid];
      is[tid] = snd[row0 + tid];
      sp[tid] = sortpos[row0 + tid];
    }
    __syncthreads();
  }

  auto load_x = [&](int kt, uint4 v[NI]) {
    #pragma unroll
    for (int i = 0; i < NI; ++i) {
      int q = wq * RPW + i * 8 + lr;
      if constexpr (MODE == 0) {
        v[i] = *(const uint4*)(e_bf + (size_t)(row0 + q) * 128 + kt * 64 + cj * 8);
      } else if constexpr (MODE == 1) {
        int gn = row0 + q;
        if (gn < NN) {
          if (kt < 2) {
            v[i] = *(const uint4*)(h_bf + (size_t)gn * 128 + kt * 64 + cj * 8);
          } else {
            const float* p = pooled + (size_t)gn * 128 + (kt - 2) * 64 + cj * 8;
            float4 a = *(const float4*)p;
            float4 b = *(const float4*)(p + 4);
            v[i].x = pk2(a.x, a.y); v[i].y = pk2(a.z, a.w);
            v[i].z = pk2(b.x, b.y); v[i].w = pk2(b.z, b.w);
          }
        } else v[i] = make_uint4(0, 0, 0, 0);
      } else if constexpr (MODE == 2) {
        int gn = row0 + q;
        float x[8];
        #pragma unroll
        for (int j = 0; j < 8; ++j) {
          int k = cj * 8 + j;
          x[j] = (gn < NN && k < 30) ? feat[(size_t)gn * 30 + k] : 0.f;
        }
        v[i].x = pk2(x[0], x[1]); v[i].y = pk2(x[2], x[3]);
        v[i].z = pk2(x[4], x[5]); v[i].w = pk2(x[6], x[7]);
      } else {
        int ge = row0 + q;
        float x[8];
        #pragma unroll
        for (int j = 0; j < 8; ++j) {
          int k = cj * 8 + j;
          x[j] = (k < 3) ? feat[(size_t)ge * 3 + k] : 0.f;
        }
        v[i].x = pk2(x[0], x[1]); v[i].y = pk2(x[2], x[3]);
        v[i].z = pk2(x[4], x[5]); v[i].w = pk2(x[6], x[7]);
      }
    }
  };
  auto load_w = [&](const u16* Wt, int kstr, int kt, uint4 v[4]) {
    #pragma unroll
    for (int i = 0; i < 4; ++i) {
      int ch = wq * 32 + i * 8 + lr;
      v[i] = *(const uint4*)(Wt + (size_t)ch * kstr + kt * 64 + cj * 8);
    }
  };
  auto stage_x = [&](int buf, const uint4 v[NI]) {
    #pragma unroll
    for (int i = 0; i < NI; ++i) {
      int q = wq * RPW + i * 8 + lr;
      int c = cj ^ (lr & 7);
      *(uint4*)&XS[buf][q * 64 + c * 8] = v[i];
    }
  };
  auto stage_w = [&](int buf, const uint4 v[4]) {
    #pragma unroll
    for (int i = 0; i < 4; ++i) {
      int q = wq * 32 + i * 8 + lr;
      int c = cj ^ (lr & 7);
      *(uint4*)&WS[buf][q * 64 + c * 8] = v[i];
    }
  };

  f32x4 acc[4][NET];
  auto init_acc = [&](const float* b) {
    #pragma unroll
    for (int ct = 0; ct < 4; ++ct) {
      f32x4 bv = {0.f, 0.f, 0.f, 0.f};
      if (b) bv = *(const f32x4*)(b + ch0 + ct * 16);
      #pragma unroll
      for (int et = 0; et < NET; ++et) acc[ct][et] = bv;
    }
  };
  auto compute_tile = [&](const u16* xbuf, const u16* wbuf) {
    #pragma unroll
    for (int k0 = 0; k0 < 2; ++k0) {
      bf16x8 wf[4], xf[NET];
      #pragma unroll
      for (int ct = 0; ct < 4; ++ct) {
        int ch = wm * 64 + ct * 16 + l15;
        wf[ct] = *(const bf16x8*)&wbuf[ch * 64 + (((k0 * 4 + lq) ^ (l15 & 7)) * 8)];
      }
      #pragma unroll
      for (int et = 0; et < NET; ++et) {
        int ed = wn * RH + et * 16 + l15;
        xf[et] = *(const bf16x8*)&xbuf[ed * 64 + (((k0 * 4 + lq) ^ (l15 & 7)) * 8)];
      }
      #pragma unroll
      for (int ct = 0; ct < 4; ++ct)
        #pragma unroll
        for (int et = 0; et < NET; ++et)
          acc[ct][et] = __builtin_amdgcn_mfma_f32_16x16x32_bf16(wf[ct], xf[et], acc[ct][et], 0, 0, 0);
    }
  };
  // write acc (optionally relu) as bf16 into XS[0..1] = [row][128 k], swizzled
  auto store_h = [&](bool relu) {
    #pragma unroll
    for (int ct = 0; ct < 4; ++ct)
      #pragma unroll
      for (int et = 0; et < NET; ++et) {
        float v0 = acc[ct][et][0], v1 = acc[ct][et][1], v2 = acc[ct][et][2], v3 = acc[ct][et][3];
        if (relu) { v0 = fmaxf(v0, 0.f); v1 = fmaxf(v1, 0.f); v2 = fmaxf(v2, 0.f); v3 = fmaxf(v3, 0.f); }
        ushort4 o = {f2bf(v0), f2bf(v1), f2bf(v2), f2bf(v3)};
        int ed = wn * RH + et * 16 + l15;
        int c3 = ct * 2 + (lq >> 1);
        int cs = c3 ^ (l15 & 7);
        *(ushort4*)&XS[wm][ed * 64 + cs * 8 + (lq & 1) * 4] = o;
      }
  };

  uint4 vx[NI], vw[4];

  // ---------------- layer 0: K0, KT0 k-tiles ----------------
  if constexpr (MODE == 0) init_acc(nullptr); else init_acc(b0);
  load_x(0, vx); load_w(Wt0, K0, 0, vw);
  stage_x(0, vx); stage_w(0, vw);
  __syncthreads();
  for (int kt = 0; kt < KT0; ++kt) {
    int cur = kt & 1, nxt = cur ^ 1;
    if (kt < KT0 - 1) { load_x(kt + 1, vx); load_w(Wt0, K0, kt + 1, vw); }
    compute_tile(XS[cur], WS[cur]);
    if (kt < KT0 - 1) { stage_x(nxt, vx); stage_w(nxt, vw); }
    __syncthreads();
  }
  // msg: add gathered node projections Ur[rcv] + Us[snd] (b0 folded into Ur)
  if constexpr (MODE == 0) {
    #pragma unroll
    for (int ct = 0; ct < 4; ++ct)
      #pragma unroll
      for (int et = 0; et < NET; ++et) {
        int ed = wn * RH + et * 16 + l15;
        f32x4 vr = *(const f32x4*)(Ur_in + (size_t)ir[ed] * 128 + ch0 + ct * 16);
        f32x4 vs = *(const f32x4*)(Us_in + (size_t)is[ed] * 128 + ch0 + ct * 16);
        acc[ct][et] += vr + vs;
      }
  }
  store_h(true);          // h1 -> XS[0..1]
  __syncthreads();

  // ---------------- layer 1: K=128, 2 k-tiles ----------------
  init_acc(b1);
  load_w(Wt1, 128, 0, vw); stage_w(0, vw);
  __syncthreads();
  for (int kt = 0; kt < 2; ++kt) {
    if (kt < 1) load_w(Wt1, 128, 1, vw);
    compute_tile(XS[kt], WS[kt]);
    if (kt < 1) stage_w(1, vw);
    __syncthreads();
  }
  store_h(true);          // h2 -> XS[0..1]
  __syncthreads();

  // ---------------- layer 2: K=128, 2 k-tiles ----------------
  init_acc(b2);
  load_w(Wt2, 128, 0, vw); stage_w(0, vw);
  __syncthreads();
  for (int kt = 0; kt < 2; ++kt) {
    if (kt < 1) load_w(Wt2, 128, 1, vw);
    compute_tile(XS[kt], WS[kt]);
    if (kt < 1) stage_w(1, vw);
    __syncthreads();
  }

  // ---------------- LayerNorm (fp32, cross-wave over wm halves) ----------------
  float ss[NET], qs[NET];
  #pragma unroll
  for (int et = 0; et < NET; ++et) {
    float s = 0.f, q = 0.f;
    #pragma unroll
    for (int ct = 0; ct < 4; ++ct)
      #pragma unroll
      for (int i = 0; i < 4; ++i) { float v = acc[ct][et][i]; s += v; q += v * v; }
    s += __shfl_xor(s, 16, 64); s += __shfl_xor(s, 32, 64);
    q += __shfl_xor(q, 16, 64); q += __shfl_xor(q, 32, 64);
    ss[et] = s; qs[et] = q;
  }
  if (lane < 16) {
    #pragma unroll
    for (int et = 0; et < NET; ++et) {
      part_s[wm][wn * RH + et * 16 + lane] = ss[et];
      part_q[wm][wn * RH + et * 16 + lane] = qs[et];
    }
  }
  __syncthreads();
  float mean[NET], inv[NET];
  #pragma unroll
  for (int et = 0; et < NET; ++et) {
    int ed = wn * RH + et * 16 + l15;
    float S = part_s[0][ed] + part_s[1][ed];
    float Q = part_q[0][ed] + part_q[1][ed];
    float m = S * (1.f / 128.f);
    float var = Q * (1.f / 128.f) - m * m;
    mean[et] = m; inv[et] = rsqrtf(var + 1e-3f);
  }
  #pragma unroll
  for (int ct = 0; ct < 4; ++ct) {
    f32x4 g4 = *(const f32x4*)(g  + ch0 + ct * 16);
    f32x4 b4 = *(const f32x4*)(be + ch0 + ct * 16);
    #pragma unroll
    for (int et = 0; et < NET; ++et)
      #pragma unroll
      for (int i = 0; i < 4; ++i)
        acc[ct][et][i] = g4[i] * (acc[ct][et][i] - mean[et]) * inv[et] + b4[i];
  }

  if constexpr (MODE == 0) {
    store_h(false);
    __syncthreads();
    int ed = tid >> 1, hf = tid & 1;
    size_t drow = (size_t)sp[ed] * 128;
    #pragma unroll
    for (int c = hf * 8; c < hf * 8 + 8; ++c) {
      int buf = c >> 3, c3 = c & 7, cs = c3 ^ (ed & 7);
      uint4 v = *(const uint4*)&XS[buf][ed * 64 + cs * 8];
      *(uint4*)(m_out + drow + c * 8) = v;
    }
  } else if constexpr (MODE == 3) {
    #pragma unroll
    for (int ct = 0; ct < 4; ++ct)
      #pragma unroll
      for (int et = 0; et < NET; ++et) {
        int gr = row0 + wn * RH + et * 16 + l15;
        f32x4 v = acc[ct][et];
        ushort4 o = {f2bf(v[0]), f2bf(v[1]), f2bf(v[2]), f2bf(v[3])};
        *(ushort4*)(hbf_out + (size_t)gr * 128 + ch0 + ct * 16) = o;
      }
  } else {
    // MODE 1: residual add into acc; MODE 1/2: write h (f32) + h_bf, then U-emit
    #pragma unroll
    for (int ct = 0; ct < 4; ++ct)
      #pragma unroll
      for (int et = 0; et < NET; ++et) {
        int gr = row0 + wn * RH + et * 16 + l15;
        if (gr < NN) {
          if constexpr (MODE == 1)
            acc[ct][et] += *(const f32x4*)(h32 + (size_t)gr * 128 + ch0 + ct * 16);
          f32x4 v = acc[ct][et];
          ushort4 o = {f2bf(v[0]), f2bf(v[1]), f2bf(v[2]), f2bf(v[3])};
          *(f32x4*)(h_out + (size_t)gr * 128 + ch0 + ct * 16) = v;
          *(ushort4*)(hbf_out + (size_t)gr * 128 + ch0 + ct * 16) = o;
        }
      }
    if (Wtr) {
      store_h(false);     // h_new -> XS[0..1]
      #pragma unroll 1
      for (int pass = 0; pass < 2; ++pass) {
        const u16* Wt = pass ? Wts : Wtr;
        float* Uo = pass ? Us_out : Ur_out;
        #pragma unroll
        for (int ct = 0; ct < 4; ++ct) {
          f32x4 bv = {0.f, 0.f, 0.f, 0.f};
          if (pass == 0) bv = *(const f32x4*)(b0n + ch0 + ct * 16);
          #pragma unroll
          for (int et = 0; et < NET; ++et) acc[ct][et] = bv;
        }
        load_w(Wt, 128, 0, vw);
        __syncthreads();                 // prior WS readers + store_h visible
        stage_w(0, vw);
        __syncthreads();
        for (int kt = 0; kt < 2; ++kt) {
          if (kt < 1) load_w(Wt, 128, 1, vw);
          compute_tile(XS[kt], WS[kt]);
          if (kt < 1) stage_w(1, vw);
          __syncthreads();
        }
        #pragma unroll
        for (int ct = 0; ct < 4; ++ct)
          #pragma unroll
          for (int et = 0; et < NET; ++et) {
            int gr = row0 + wn * RH + et * 16 + l15;
            if (gr < NN)
              *(f32x4*)(Uo + (size_t)gr * 128 + ch0 + ct * 16) = acc[ct][et];
          }
      }
    }
  }
}

// ===========================================================================
extern "C" void kernel_launch(void* const* d_in, const int* in_sizes, int n_in,
                              void* d_out, int out_size, void* d_ws, size_t ws_size,
                              hipStream_t stream) {
  int i = 0;
  const float* node_feat = (const float*)d_in[i++];
  const float* edge_feat = (const float*)d_in[i++];
  const int*   senders   = (const int*)d_in[i++];
  const int*   receivers = (const int*)d_in[i++];
  const float *encn_W0 = (const float*)d_in[i++], *encn_b0 = (const float*)d_in[i++],
              *encn_W1 = (const float*)d_in[i++], *encn_b1 = (const float*)d_in[i++],
              *encn_W2 = (const float*)d_in[i++], *encn_b2 = (const float*)d_in[i++],
              *encn_g  = (const float*)d_in[i++], *encn_be = (const float*)d_in[i++];
  const float *ence_W0 = (const float*)d_in[i++], *ence_b0 = (const float*)d_in[i++],
              *ence_W1 = (const float*)d_in[i++], *ence_b1 = (const float*)d_in[i++],
              *ence_W2 = (const float*)d_in[i++], *ence_b2 = (const float*)d_in[i++],
              *ence_g  = (const float*)d_in[i++], *ence_be = (const float*)d_in[i++];
  const float *msg_W0 = (const float*)d_in[i++], *msg_b0 = (const float*)d_in[i++],
              *msg_W1 = (const float*)d_in[i++], *msg_b1 = (const float*)d_in[i++],
              *msg_W2 = (const float*)d_in[i++], *msg_b2 = (const float*)d_in[i++],
              *msg_g  = (const float*)d_in[i++], *msg_be = (const float*)d_in[i++];
  const float *upd_W0 = (const float*)d_in[i++], *upd_b0 = (const float*)d_in[i++],
              *upd_W1 = (const float*)d_in[i++], *upd_b1 = (const float*)d_in[i++],
              *upd_W2 = (const float*)d_in[i++], *upd_b2 = (const float*)d_in[i++],
              *upd_g  = (const float*)d_in[i++], *upd_be = (const float*)d_in[i++];
  const float *dec_W0 = (const float*)d_in[i++], *dec_b0 = (const float*)d_in[i++],
              *dec_W1 = (const float*)d_in[i++], *dec_b1 = (const float*)d_in[i++],
              *dec_W2 = (const float*)d_in[i++], *dec_b2 = (const float*)d_in[i++];

  // workspace layout (~69 MB)
  char* w = (char*)d_ws;
  float* h      = (float*)w;            w += (size_t)NN * 128 * 4;
  float* pooled = (float*)w;            w += (size_t)NN * 128 * 4;
  float* Ur     = (float*)w;            w += (size_t)NN * 128 * 4;
  float* Us     = (float*)w;            w += (size_t)NN * 128 * 4;
  u16*   h_bf   = (u16*)w;              w += (size_t)NN * 128 * 2;
  u16*   e_bf   = (u16*)w;              w += (size_t)EE * 128 * 2;
  u16*   m_buf  = (u16*)w;              w += (size_t)EE * 128 * 2;
  u16*   mWt0e  = (u16*)w;              w += (size_t)10 * 128 * 128 * 2;
  u16*   mWt1   = (u16*)w;              w += (size_t)10 * 128 * 128 * 2;
  u16*   mWt2   = (u16*)w;              w += (size_t)10 * 128 * 128 * 2;
  u16*   pWtr   = (u16*)w;              w += (size_t)10 * 128 * 128 * 2;
  u16*   pWts   = (u16*)w;              w += (size_t)10 * 128 * 128 * 2;
  u16*   uWt0   = (u16*)w;              w += (size_t)10 * 128 * 256 * 2;
  u16*   uWt1   = (u16*)w;              w += (size_t)10 * 128 * 128 * 2;
  u16*   uWt2   = (u16*)w;              w += (size_t)10 * 128 * 128 * 2;
  u16*   nWt0   = (u16*)w;              w += (size_t)128 * 64 * 2;
  u16*   nWt1   = (u16*)w;              w += (size_t)128 * 128 * 2;
  u16*   nWt2   = (u16*)w;              w += (size_t)128 * 128 * 2;
  u16*   eWt0   = (u16*)w;              w += (size_t)128 * 64 * 2;
  u16*   eWt1   = (u16*)w;              w += (size_t)128 * 128 * 2;
  u16*   eWt2   = (u16*)w;              w += (size_t)128 * 128 * 2;
  int*   cnt    = (int*)w;              w += (size_t)NN * 4;
  int*   offs   = (int*)w;              w += (size_t)(NN + 1) * 4;
  int*   curs   = (int*)w;              w += (size_t)NN * 4;
  int*   sortp  = (int*)w;              w += (size_t)EE * 4;

  const int NB_N64 = (NN + 63) / 64;     // 157
  const int NB_E128 = EE / 128;          // 625
  const int NB_E256 = (EE + 255) / 256;

  // CSR build (once per launch)
  hipMemsetAsync(cnt, 0, (size_t)NN * 4, stream);
  hist_k<<<NB_E256, 256, 0, stream>>>(receivers, cnt);
  scan_k<<<1, 1024, 0, stream>>>(cnt, offs, curs);
  scatter_k<<<NB_E256, 256, 0, stream>>>(receivers, curs, sortp);

  // weight pre-transposes (bf16 W^T). msg W0 split: rows 0-127 rcv, 128-255 snd, 256-383 e
  wtrans_k<<<10 * 4 * 4, 256, 0, stream>>>(msg_W0,             pWtr,  128, 384 * 128);
  wtrans_k<<<10 * 4 * 4, 256, 0, stream>>>(msg_W0 + 128 * 128, pWts,  128, 384 * 128);
  wtrans_k<<<10 * 4 * 4, 256, 0, stream>>>(msg_W0 + 256 * 128, mWt0e, 128, 384 * 128);
  wtrans_k<<<10 * 4 * 4, 256, 0, stream>>>(msg_W1, mWt1, 128, 128 * 128);
  wtrans_k<<<10 * 4 * 4, 256, 0, stream>>>(msg_W2, mWt2, 128, 128 * 128);
  wtrans_k<<<10 * 8 * 4, 256, 0, stream>>>(upd_W0, uWt0, 256, 256 * 128);
  wtrans_k<<<10 * 4 * 4, 256, 0, stream>>>(upd_W1, uWt1, 128, 128 * 128);
  wtrans_k<<<10 * 4 * 4, 256, 0, stream>>>(upd_W2, uWt2, 128, 128 * 128);
  wtrans_pad_k<<<1, 128, 0, stream>>>(encn_W0, nWt0, 30);
  wtrans_k<<<4 * 4, 256, 0, stream>>>(encn_W1, nWt1, 128, 128 * 128);
  wtrans_k<<<4 * 4, 256, 0, stream>>>(encn_W2, nWt2, 128, 128 * 128);
  wtrans_pad_k<<<1, 128, 0, stream>>>(ence_W0, eWt0, 3);
  wtrans_k<<<4 * 4, 256, 0, stream>>>(ence_W1, eWt1, 128, 128 * 128);
  wtrans_k<<<4 * 4, 256, 0, stream>>>(ence_W2, eWt2, 128, 128 * 128);

  // node encoder (+ U-emit for round 0)
  mlp3_mfma_k<2, 1, 64><<<NB_N64, 256, 0, stream>>>(
      nullptr, nullptr, nullptr, nullptr, node_feat, nullptr, nullptr, nullptr,
      nullptr, nullptr,
      nWt0, encn_b0, nWt1, encn_b1, nWt2, encn_b2, encn_g, encn_be,
      pWtr, pWts, msg_b0,
      nullptr, h, h_bf, Ur, Us);
  // edge encoder
  mlp3_mfma_k<3, 1, 128><<<NB_E128, 256, 0, stream>>>(
      nullptr, nullptr, nullptr, nullptr, edge_feat, nullptr, nullptr, nullptr,
      nullptr, nullptr,
      eWt0, ence_b0, eWt1, ence_b1, eWt2, ence_b2, ence_g, ence_be,
      nullptr, nullptr, nullptr,
      nullptr, nullptr, e_bf, nullptr, nullptr);

  for (int t = 0; t < TT; ++t) {
    mlp3_mfma_k<0, 2, 128><<<NB_E128, 256, 0, stream>>>(
        nullptr, e_bf, nullptr, nullptr, nullptr, senders, receivers, sortp,
        Ur, Us,
        mWt0e + (size_t)t * 128 * 128, nullptr,
        mWt1  + (size_t)t * 128 * 128, msg_b1 + (size_t)t * 128,
        mWt2  + (size_t)t * 128 * 128, msg_b2 + (size_t)t * 128,
        msg_g + (size_t)t * 128, msg_be + (size_t)t * 128,
        nullptr, nullptr, nullptr,
        m_buf, nullptr, nullptr, nullptr, nullptr);
    pool_k<<<NN / 4, 256, 0, stream>>>(m_buf, offs, pooled);
    bool last = (t == TT - 1);
    mlp3_mfma_k<1, 4, 64><<<NB_N64, 256, 0, stream>>>(
        h_bf, nullptr, h, pooled, nullptr, nullptr, nullptr, nullptr,
        nullptr, nullptr,
        uWt0 + (size_t)t * 128 * 256, upd_b0 + (size_t)t * 128,
        uWt1 + (size_t)t * 128 * 128, upd_b1 + (size_t)t * 128,
        uWt2 + (size_t)t * 128 * 128, upd_b2 + (size_t)t * 128,
        upd_g + (size_t)t * 128, upd_be + (size_t)t * 128,
        last ? nullptr : (pWtr + (size_t)(t + 1) * 128 * 128),
        last ? nullptr : (pWts + (size_t)(t + 1) * 128 * 128),
        last ? nullptr : (msg_b0 + (size_t)(t + 1) * 128),
        nullptr, h, h_bf, Ur, Us);
  }
  dec_k<<<(NN + 31) / 32, 256, 0, stream>>>(h, dec_W0, dec_b0, dec_W1, dec_b1,
                                            dec_W2, dec_b2, (float*)d_out);
}

// Round 6
// 790.379 us; speedup vs baseline: 4.4258x; 1.0447x over previous
//
#include <hip/hip_runtime.h>

#define NN 10000
#define EE 80000
#define TT 10

typedef unsigned short u16;
typedef unsigned int u32;
using f32x4  = __attribute__((ext_vector_type(4))) float;
using bf16x8 = __attribute__((ext_vector_type(8))) short;

__device__ __forceinline__ u16 f2bf(float f) {
  union { float f; u32 u; } v; v.f = f;
  return (u16)((v.u + 0x7fffu + ((v.u >> 16) & 1u)) >> 16);   // RNE
}
__device__ __forceinline__ u32 pk2(float lo, float hi) {
  return (u32)f2bf(lo) | ((u32)f2bf(hi) << 16);
}
__device__ __forceinline__ float bflo(u32 v) { union { u32 u; float f; } x; x.u = v << 16; return x.f; }
__device__ __forceinline__ float bfhi(u32 v) { union { u32 u; float f; } x; x.u = v & 0xffff0000u; return x.f; }

// ===========================================================================
// fp32 helpers (dec only)
// ===========================================================================

__device__ __forceinline__ void initacc(const float* __restrict__ b, int tid, float acc[4][4]) {
  const int j0 = (tid & 31) * 4;
  float4 b4 = *(const float4*)(b + j0);
  #pragma unroll
  for (int rr = 0; rr < 4; ++rr) {
    acc[rr][0] = b4.x; acc[rr][1] = b4.y; acc[rr][2] = b4.z; acc[rr][3] = b4.w;
  }
}

template<int K, int SX, bool RELU>
__device__ __forceinline__ void gemm32(const float* __restrict__ W,
                                       const float* __restrict__ b,
                                       const float* __restrict__ xs,
                                       float acc[4][4], int tid) {
  const int j0 = (tid & 31) * 4;
  const int r0 = (tid >> 5) * 4;
  initacc(b, tid, acc);
  #pragma unroll 2
  for (int k = 0; k < K; k += 4) {
    float4 x[4];
    #pragma unroll
    for (int rr = 0; rr < 4; ++rr) x[rr] = *(const float4*)(xs + (r0 + rr) * SX + k);
    #pragma unroll
    for (int kk = 0; kk < 4; ++kk) {
      float4 w = *(const float4*)(W + (size_t)(k + kk) * 128 + j0);
      #pragma unroll
      for (int rr = 0; rr < 4; ++rr) {
        float xv = (kk == 0) ? x[rr].x : (kk == 1) ? x[rr].y : (kk == 2) ? x[rr].z : x[rr].w;
        acc[rr][0] = fmaf(xv, w.x, acc[rr][0]);
        acc[rr][1] = fmaf(xv, w.y, acc[rr][1]);
        acc[rr][2] = fmaf(xv, w.z, acc[rr][2]);
        acc[rr][3] = fmaf(xv, w.w, acc[rr][3]);
      }
    }
  }
  if (RELU) {
    #pragma unroll
    for (int rr = 0; rr < 4; ++rr)
      #pragma unroll
      for (int c = 0; c < 4; ++c)
        acc[rr][c] = acc[rr][c] > 0.f ? acc[rr][c] : 0.f;
  }
}

__device__ __forceinline__ void store32(const float acc[4][4], float* out, int tid) {
  const int j0 = (tid & 31) * 4;
  const int r0 = (tid >> 5) * 4;
  #pragma unroll
  for (int rr = 0; rr < 4; ++rr) {
    float4 v = {acc[rr][0], acc[rr][1], acc[rr][2], acc[rr][3]};
    *(float4*)(out + (r0 + rr) * 128 + j0) = v;
  }
}

// decoder: h -> MLP(128->128->128->3) -> out  (fp32)
__global__ __launch_bounds__(256) void dec_k(
    const float* __restrict__ h,
    const float* __restrict__ W0, const float* __restrict__ b0,
    const float* __restrict__ W1, const float* __restrict__ b1,
    const float* __restrict__ W2, const float* __restrict__ b2,
    float* __restrict__ out) {
  __shared__ float xs[32 * 128];
  __shared__ float hb0[32 * 128];
  float* hb1 = xs;
  const int tid = threadIdx.x;
  const int row0 = blockIdx.x * 32;
  for (int q = tid; q < 32 * 32; q += 256) {
    int r = q >> 5, c = q & 31;
    int gn = row0 + r;
    float4 v = {0.f, 0.f, 0.f, 0.f};
    if (gn < NN) v = *(const float4*)(h + (size_t)gn * 128 + c * 4);
    *(float4*)(xs + r * 128 + c * 4) = v;
  }
  __syncthreads();
  float acc[4][4];
  gemm32<128, 128, true>(W0, b0, xs, acc, tid);  store32(acc, hb0, tid); __syncthreads();
  gemm32<128, 128, true>(W1, b1, hb0, acc, tid); store32(acc, hb1, tid); __syncthreads();
  if (tid < 96) {
    int r = tid / 3, o = tid - (tid / 3) * 3;
    int gn = row0 + r;
    float a = b2[o];
    for (int k = 0; k < 128; ++k) a = fmaf(hb1[r * 128 + k], W2[k * 3 + o], a);
    if (gn < NN) out[(size_t)gn * 3 + o] = a;
  }
}

// ===========================================================================
// CSR build (per-launch; deterministic work)
// ===========================================================================

__global__ __launch_bounds__(256) void hist_k(const int* __restrict__ rcv, int* __restrict__ cnt) {
  int e = blockIdx.x * 256 + threadIdx.x;
  if (e < EE) atomicAdd(&cnt[rcv[e]], 1);
}

__global__ __launch_bounds__(1024) void scan_k(const int* __restrict__ cnt,
                                               int* __restrict__ offs, int* __restrict__ curs) {
  __shared__ int ps[1024];
  const int t = threadIdx.x;
  int loc[10], s = 0;
  #pragma unroll
  for (int j = 0; j < 10; ++j) {
    int idx = t * 10 + j;
    int v = (idx < NN) ? cnt[idx] : 0;
    loc[j] = s; s += v;
  }
  ps[t] = s;
  __syncthreads();
  for (int off = 1; off < 1024; off <<= 1) {
    int v = (t >= off) ? ps[t - off] : 0;
    __syncthreads();
    ps[t] += v;
    __syncthreads();
  }
  int pre = (t == 0) ? 0 : ps[t - 1];
  #pragma unroll
  for (int j = 0; j < 10; ++j) {
    int idx = t * 10 + j;
    if (idx < NN) { int o = pre + loc[j]; offs[idx] = o; curs[idx] = o; }
  }
  if (t == 1023) offs[NN] = ps[1023];
}

// also emits receiver-sorted index arrays: rcv_s[p], snd_s[p]
__global__ __launch_bounds__(256) void scatter_k(const int* __restrict__ rcv,
                                                 const int* __restrict__ snd,
                                                 int* __restrict__ curs,
                                                 int* __restrict__ sortpos,
                                                 int* __restrict__ rcv_s,
                                                 int* __restrict__ snd_s) {
  int e = blockIdx.x * 256 + threadIdx.x;
  if (e < EE) {
    int r = rcv[e];
    int p = atomicAdd(&curs[r], 1);
    sortpos[e] = p;
    rcv_s[p] = r;
    snd_s[p] = snd[e];
  }
}

// segment-sum: one wave per node; m_buf rows are receiver-sorted -> contiguous
__global__ __launch_bounds__(256) void pool_k(const u16* __restrict__ m,
                                              const int* __restrict__ offs,
                                              float* __restrict__ pooled) {
  const int lane = threadIdx.x & 63;
  const int n = blockIdx.x * 4 + (threadIdx.x >> 6);
  const int j0 = offs[n], j1 = offs[n + 1];
  float a0 = 0.f, a1 = 0.f;
  int j = j0;
  for (; j + 4 <= j1; j += 4) {
    u32 v0 = *(const u32*)(m + (size_t)(j + 0) * 128 + lane * 2);
    u32 v1 = *(const u32*)(m + (size_t)(j + 1) * 128 + lane * 2);
    u32 v2 = *(const u32*)(m + (size_t)(j + 2) * 128 + lane * 2);
    u32 v3 = *(const u32*)(m + (size_t)(j + 3) * 128 + lane * 2);
    a0 += bflo(v0) + bflo(v1) + bflo(v2) + bflo(v3);
    a1 += bfhi(v0) + bfhi(v1) + bfhi(v2) + bfhi(v3);
  }
  for (; j < j1; ++j) {
    u32 v = *(const u32*)(m + (size_t)j * 128 + lane * 2);
    a0 += bflo(v); a1 += bfhi(v);
  }
  float2 o = {a0, a1};
  *(float2*)(pooled + (size_t)n * 128 + lane * 2) = o;
}

// ===========================================================================
// weight pre-transpose: dst[t][n][k] = bf16(src[t*tstr + k*128 + n])
// ===========================================================================
__global__ __launch_bounds__(256) void wtrans_k(const float* __restrict__ src,
                                                u16* __restrict__ dst, int K, long tstr) {
  __shared__ float tile[32][33];
  const int tiles_per_t = (K / 32) * 4;
  const int t  = blockIdx.x / tiles_per_t;
  const int rem = blockIdx.x - t * tiles_per_t;
  const int kt = rem >> 2, nt = rem & 3;
  const float* s = src + (size_t)t * tstr;
  u16* d = dst + (size_t)t * 128 * K;
  const int r = threadIdx.x >> 5, c = threadIdx.x & 31;
  for (int rr = r; rr < 32; rr += 8)
    tile[rr][c] = s[(size_t)(kt * 32 + rr) * 128 + nt * 32 + c];
  __syncthreads();
  for (int rr = r; rr < 32; rr += 8)
    d[(size_t)(nt * 32 + rr) * K + kt * 32 + c] = f2bf(tile[c][rr]);
}

// small-K pad transpose: dst[n][k<64] = k<K ? bf16(src[k][n]) : 0   (1 block)
__global__ __launch_bounds__(128) void wtrans_pad_k(const float* __restrict__ src,
                                                    u16* __restrict__ dst, int K) {
  const int ch = threadIdx.x;
  for (int k = 0; k < 64; ++k)
    dst[ch * 64 + k] = (k < K) ? f2bf(src[(size_t)k * 128 + ch]) : (u16)0;
}

// ===========================================================================
// unified MFMA MLP3(+LN) kernel: BM rows x 128 ch per block, BK=64
//   MODE 0 = msg   (edges RECEIVER-SORTED: stage e_bf seq, L0=e@W0e,
//                   + reg-preloaded Ur[rcv_s]+Us[snd_s], out m_buf seq)
//   MODE 1 = upd   (stage h_bf|pooled, residual, out h+h_bf, optional U-emit)
//   MODE 2 = encn  (stage node_feat, out h+h_bf, optional U-emit)
//   MODE 3 = ence  (stage edge_feat, out e_bf[sortpos] scatter)
// U-emit (MODE 1/2, Wtr!=null): Ur = h_new@Wtr^T + b0n; Us = h_new@Wts^T  (fp32)
// ===========================================================================
template<int MODE, int KT0, int BM>
__global__ __launch_bounds__(256, 2) void mlp3_mfma_k(
    const u16* __restrict__ h_bf, const u16* __restrict__ e_bf,
    const float* __restrict__ h32, const float* __restrict__ pooled,
    const float* __restrict__ feat,
    const int* __restrict__ snd, const int* __restrict__ rcv,
    const int* __restrict__ sortpos,
    const float* __restrict__ Ur_in, const float* __restrict__ Us_in,
    const u16* __restrict__ Wt0, const float* __restrict__ b0,
    const u16* __restrict__ Wt1, const float* __restrict__ b1,
    const u16* __restrict__ Wt2, const float* __restrict__ b2,
    const float* __restrict__ g,  const float* __restrict__ be,
    const u16* __restrict__ Wtr, const u16* __restrict__ Wts,
    const float* __restrict__ b0n,
    u16* __restrict__ m_out, float* __restrict__ h_out, u16* __restrict__ hbf_out,
    float* __restrict__ Ur_out, float* __restrict__ Us_out) {
  constexpr int K0  = KT0 * 64;
  constexpr int RPW = BM / 4;     // rows staged per wave
  constexpr int NI  = RPW / 8;    // staging iterations
  constexpr int RH  = BM / 2;     // rows per wn-half
  constexpr int NET = RH / 16;    // 16-row tiles per wave

  __shared__ u16 XS[2][BM * 64];
  __shared__ u16 WS[2][128 * 64];
  __shared__ float part_s[2][BM], part_q[2][BM];

  const int tid = threadIdx.x;
  const int lane = tid & 63;
  const int wq = tid >> 6;
  const int wm = wq >> 1, wn = wq & 1;
  const int l15 = lane & 15, lq = lane >> 4;
  const int row0 = blockIdx.x * BM;
  const int lr = lane >> 3;
  const int cj = lane & 7;
  const int ch0 = wm * 64 + lq * 4;

  // ---- MODE 0: T14 async gather of node projections (issue NOW, use after L0)
  f32x4 ur[4][(MODE == 0) ? NET : 1], us[4][(MODE == 0) ? NET : 1];
  if constexpr (MODE == 0) {
    #pragma unroll
    for (int et = 0; et < NET; ++et) {
      int j = row0 + wn * RH + et * 16 + l15;
      int nr = rcv[j];                       // rcv = rcv_s (sorted: high locality)
      int ns = snd[j];                       // snd = snd_s (random)
      #pragma unroll
      for (int ct = 0; ct < 4; ++ct) {
        ur[ct][et] = *(const f32x4*)(Ur_in + (size_t)nr * 128 + ch0 + ct * 16);
        us[ct][et] = *(const f32x4*)(Us_in + (size_t)ns * 128 + ch0 + ct * 16);
      }
    }
  }

  auto load_x = [&](int kt, uint4 v[NI]) {
    #pragma unroll
    for (int i = 0; i < NI; ++i) {
      int q = wq * RPW + i * 8 + lr;
      if constexpr (MODE == 0) {
        v[i] = *(const uint4*)(e_bf + (size_t)(row0 + q) * 128 + kt * 64 + cj * 8);
      } else if constexpr (MODE == 1) {
        int gn = row0 + q;
        if (gn < NN) {
          if (kt < 2) {
            v[i] = *(const uint4*)(h_bf + (size_t)gn * 128 + kt * 64 + cj * 8);
          } else {
            const float* p = pooled + (size_t)gn * 128 + (kt - 2) * 64 + cj * 8;
            float4 a = *(const float4*)p;
            float4 b = *(const float4*)(p + 4);
            v[i].x = pk2(a.x, a.y); v[i].y = pk2(a.z, a.w);
            v[i].z = pk2(b.x, b.y); v[i].w = pk2(b.z, b.w);
          }
        } else v[i] = make_uint4(0, 0, 0, 0);
      } else if constexpr (MODE == 2) {
        int gn = row0 + q;
        float x[8];
        #pragma unroll
        for (int j = 0; j < 8; ++j) {
          int k = cj * 8 + j;
          x[j] = (gn < NN && k < 30) ? feat[(size_t)gn * 30 + k] : 0.f;
        }
        v[i].x = pk2(x[0], x[1]); v[i].y = pk2(x[2], x[3]);
        v[i].z = pk2(x[4], x[5]); v[i].w = pk2(x[6], x[7]);
      } else {
        int ge = row0 + q;
        float x[8];
        #pragma unroll
        for (int j = 0; j < 8; ++j) {
          int k = cj * 8 + j;
          x[j] = (k < 3) ? feat[(size_t)ge * 3 + k] : 0.f;
        }
        v[i].x = pk2(x[0], x[1]); v[i].y = pk2(x[2], x[3]);
        v[i].z = pk2(x[4], x[5]); v[i].w = pk2(x[6], x[7]);
      }
    }
  };
  auto load_w = [&](const u16* Wt, int kstr, int kt, uint4 v[4]) {
    #pragma unroll
    for (int i = 0; i < 4; ++i) {
      int ch = wq * 32 + i * 8 + lr;
      v[i] = *(const uint4*)(Wt + (size_t)ch * kstr + kt * 64 + cj * 8);
    }
  };
  auto stage_x = [&](int buf, const uint4 v[NI]) {
    #pragma unroll
    for (int i = 0; i < NI; ++i) {
      int q = wq * RPW + i * 8 + lr;
      int c = cj ^ (lr & 7);
      *(uint4*)&XS[buf][q * 64 + c * 8] = v[i];
    }
  };
  auto stage_w = [&](int buf, const uint4 v[4]) {
    #pragma unroll
    for (int i = 0; i < 4; ++i) {
      int q = wq * 32 + i * 8 + lr;
      int c = cj ^ (lr & 7);
      *(uint4*)&WS[buf][q * 64 + c * 8] = v[i];
    }
  };

  f32x4 acc[4][NET];
  auto init_acc = [&](const float* b) {
    #pragma unroll
    for (int ct = 0; ct < 4; ++ct) {
      f32x4 bv = {0.f, 0.f, 0.f, 0.f};
      if (b) bv = *(const f32x4*)(b + ch0 + ct * 16);
      #pragma unroll
      for (int et = 0; et < NET; ++et) acc[ct][et] = bv;
    }
  };
  auto compute_tile = [&](const u16* xbuf, const u16* wbuf) {
    #pragma unroll
    for (int k0 = 0; k0 < 2; ++k0) {
      bf16x8 wf[4], xf[NET];
      #pragma unroll
      for (int ct = 0; ct < 4; ++ct) {
        int ch = wm * 64 + ct * 16 + l15;
        wf[ct] = *(const bf16x8*)&wbuf[ch * 64 + (((k0 * 4 + lq) ^ (l15 & 7)) * 8)];
      }
      #pragma unroll
      for (int et = 0; et < NET; ++et) {
        int ed = wn * RH + et * 16 + l15;
        xf[et] = *(const bf16x8*)&xbuf[ed * 64 + (((k0 * 4 + lq) ^ (l15 & 7)) * 8)];
      }
      #pragma unroll
      for (int ct = 0; ct < 4; ++ct)
        #pragma unroll
        for (int et = 0; et < NET; ++et)
          acc[ct][et] = __builtin_amdgcn_mfma_f32_16x16x32_bf16(wf[ct], xf[et], acc[ct][et], 0, 0, 0);
    }
  };
  // write acc (optionally relu) as bf16 into XS[0..1] = [row][128 k], swizzled
  auto store_h = [&](bool relu) {
    #pragma unroll
    for (int ct = 0; ct < 4; ++ct)
      #pragma unroll
      for (int et = 0; et < NET; ++et) {
        float v0 = acc[ct][et][0], v1 = acc[ct][et][1], v2 = acc[ct][et][2], v3 = acc[ct][et][3];
        if (relu) { v0 = fmaxf(v0, 0.f); v1 = fmaxf(v1, 0.f); v2 = fmaxf(v2, 0.f); v3 = fmaxf(v3, 0.f); }
        ushort4 o = {f2bf(v0), f2bf(v1), f2bf(v2), f2bf(v3)};
        int ed = wn * RH + et * 16 + l15;
        int c3 = ct * 2 + (lq >> 1);
        int cs = c3 ^ (l15 & 7);
        *(ushort4*)&XS[wm][ed * 64 + cs * 8 + (lq & 1) * 4] = o;
      }
  };

  uint4 vx[NI], vw[4];

  // ---------------- layer 0: K0, KT0 k-tiles ----------------
  if constexpr (MODE == 0) init_acc(nullptr); else init_acc(b0);
  load_x(0, vx); load_w(Wt0, K0, 0, vw);
  stage_x(0, vx); stage_w(0, vw);
  __syncthreads();
  for (int kt = 0; kt < KT0; ++kt) {
    int cur = kt & 1, nxt = cur ^ 1;
    if (kt < KT0 - 1) { load_x(kt + 1, vx); load_w(Wt0, K0, kt + 1, vw); }
    compute_tile(XS[cur], WS[cur]);
    if (kt < KT0 - 1) { stage_x(nxt, vx); stage_w(nxt, vw); }
    __syncthreads();
  }
  // msg: add preloaded node projections (b0 folded into Ur)
  if constexpr (MODE == 0) {
    #pragma unroll
    for (int ct = 0; ct < 4; ++ct)
      #pragma unroll
      for (int et = 0; et < NET; ++et)
        acc[ct][et] += ur[ct][et] + us[ct][et];
  }
  store_h(true);          // h1 -> XS[0..1]
  __syncthreads();

  // ---------------- layer 1: K=128, 2 k-tiles ----------------
  init_acc(b1);
  load_w(Wt1, 128, 0, vw); stage_w(0, vw);
  __syncthreads();
  for (int kt = 0; kt < 2; ++kt) {
    if (kt < 1) load_w(Wt1, 128, 1, vw);
    compute_tile(XS[kt], WS[kt]);
    if (kt < 1) stage_w(1, vw);
    __syncthreads();
  }
  store_h(true);          // h2 -> XS[0..1]
  __syncthreads();

  // ---------------- layer 2: K=128, 2 k-tiles ----------------
  init_acc(b2);
  load_w(Wt2, 128, 0, vw); stage_w(0, vw);
  __syncthreads();
  for (int kt = 0; kt < 2; ++kt) {
    if (kt < 1) load_w(Wt2, 128, 1, vw);
    compute_tile(XS[kt], WS[kt]);
    if (kt < 1) stage_w(1, vw);
    __syncthreads();
  }

  // ---------------- LayerNorm (fp32, cross-wave over wm halves) ----------------
  float ss[NET], qs[NET];
  #pragma unroll
  for (int et = 0; et < NET; ++et) {
    float s = 0.f, q = 0.f;
    #pragma unroll
    for (int ct = 0; ct < 4; ++ct)
      #pragma unroll
      for (int i = 0; i < 4; ++i) { float v = acc[ct][et][i]; s += v; q += v * v; }
    s += __shfl_xor(s, 16, 64); s += __shfl_xor(s, 32, 64);
    q += __shfl_xor(q, 16, 64); q += __shfl_xor(q, 32, 64);
    ss[et] = s; qs[et] = q;
  }
  if (lane < 16) {
    #pragma unroll
    for (int et = 0; et < NET; ++et) {
      part_s[wm][wn * RH + et * 16 + lane] = ss[et];
      part_q[wm][wn * RH + et * 16 + lane] = qs[et];
    }
  }
  __syncthreads();
  float mean[NET], inv[NET];
  #pragma unroll
  for (int et = 0; et < NET; ++et) {
    int ed = wn * RH + et * 16 + l15;
    float S = part_s[0][ed] + part_s[1][ed];
    float Q = part_q[0][ed] + part_q[1][ed];
    float m = S * (1.f / 128.f);
    float var = Q * (1.f / 128.f) - m * m;
    mean[et] = m; inv[et] = rsqrtf(var + 1e-3f);
  }
  #pragma unroll
  for (int ct = 0; ct < 4; ++ct) {
    f32x4 g4 = *(const f32x4*)(g  + ch0 + ct * 16);
    f32x4 b4 = *(const f32x4*)(be + ch0 + ct * 16);
    #pragma unroll
    for (int et = 0; et < NET; ++et)
      #pragma unroll
      for (int i = 0; i < 4; ++i)
        acc[ct][et][i] = g4[i] * (acc[ct][et][i] - mean[et]) * inv[et] + b4[i];
  }

  if constexpr (MODE == 0) {
    store_h(false);
    __syncthreads();
    // sequential write: m_buf row = sorted edge index = row0 + ed
    int ed = tid >> 1, hf = tid & 1;
    size_t drow = (size_t)(row0 + ed) * 128;
    #pragma unroll
    for (int c = hf * 8; c < hf * 8 + 8; ++c) {
      int buf = c >> 3, c3 = c & 7, cs = c3 ^ (ed & 7);
      uint4 v = *(const uint4*)&XS[buf][ed * 64 + cs * 8];
      *(uint4*)(m_out + drow + c * 8) = v;
    }
  } else if constexpr (MODE == 3) {
    // scatter into receiver-sorted order
    int gp[NET];
    #pragma unroll
    for (int et = 0; et < NET; ++et)
      gp[et] = sortpos[row0 + wn * RH + et * 16 + l15];
    #pragma unroll
    for (int ct = 0; ct < 4; ++ct)
      #pragma unroll
      for (int et = 0; et < NET; ++et) {
        f32x4 v = acc[ct][et];
        ushort4 o = {f2bf(v[0]), f2bf(v[1]), f2bf(v[2]), f2bf(v[3])};
        *(ushort4*)(hbf_out + (size_t)gp[et] * 128 + ch0 + ct * 16) = o;
      }
  } else {
    // MODE 1: residual add into acc; MODE 1/2: write h (f32) + h_bf, then U-emit
    #pragma unroll
    for (int ct = 0; ct < 4; ++ct)
      #pragma unroll
      for (int et = 0; et < NET; ++et) {
        int gr = row0 + wn * RH + et * 16 + l15;
        if (gr < NN) {
          if constexpr (MODE == 1)
            acc[ct][et] += *(const f32x4*)(h32 + (size_t)gr * 128 + ch0 + ct * 16);
          f32x4 v = acc[ct][et];
          ushort4 o = {f2bf(v[0]), f2bf(v[1]), f2bf(v[2]), f2bf(v[3])};
          *(f32x4*)(h_out + (size_t)gr * 128 + ch0 + ct * 16) = v;
          *(ushort4*)(hbf_out + (size_t)gr * 128 + ch0 + ct * 16) = o;
        }
      }
    if (Wtr) {
      store_h(false);     // h_new -> XS[0..1]
      #pragma unroll 1
      for (int pass = 0; pass < 2; ++pass) {
        const u16* Wt = pass ? Wts : Wtr;
        float* Uo = pass ? Us_out : Ur_out;
        #pragma unroll
        for (int ct = 0; ct < 4; ++ct) {
          f32x4 bv = {0.f, 0.f, 0.f, 0.f};
          if (pass == 0) bv = *(const f32x4*)(b0n + ch0 + ct * 16);
          #pragma unroll
          for (int et = 0; et < NET; ++et) acc[ct][et] = bv;
        }
        load_w(Wt, 128, 0, vw);
        __syncthreads();                 // prior WS readers + store_h visible
        stage_w(0, vw);
        __syncthreads();
        for (int kt = 0; kt < 2; ++kt) {
          if (kt < 1) load_w(Wt, 128, 1, vw);
          compute_tile(XS[kt], WS[kt]);
          if (kt < 1) stage_w(1, vw);
          __syncthreads();
        }
        #pragma unroll
        for (int ct = 0; ct < 4; ++ct)
          #pragma unroll
          for (int et = 0; et < NET; ++et) {
            int gr = row0 + wn * RH + et * 16 + l15;
            if (gr < NN)
              *(f32x4*)(Uo + (size_t)gr * 128 + ch0 + ct * 16) = acc[ct][et];
          }
      }
    }
  }
}

// ===========================================================================
extern "C" void kernel_launch(void* const* d_in, const int* in_sizes, int n_in,
                              void* d_out, int out_size, void* d_ws, size_t ws_size,
                              hipStream_t stream) {
  int i = 0;
  const float* node_feat = (const float*)d_in[i++];
  const float* edge_feat = (const float*)d_in[i++];
  const int*   senders   = (const int*)d_in[i++];
  const int*   receivers = (const int*)d_in[i++];
  const float *encn_W0 = (const float*)d_in[i++], *encn_b0 = (const float*)d_in[i++],
              *encn_W1 = (const float*)d_in[i++], *encn_b1 = (const float*)d_in[i++],
              *encn_W2 = (const float*)d_in[i++], *encn_b2 = (const float*)d_in[i++],
              *encn_g  = (const float*)d_in[i++], *encn_be = (const float*)d_in[i++];
  const float *ence_W0 = (const float*)d_in[i++], *ence_b0 = (const float*)d_in[i++],
              *ence_W1 = (const float*)d_in[i++], *ence_b1 = (const float*)d_in[i++],
              *ence_W2 = (const float*)d_in[i++], *ence_b2 = (const float*)d_in[i++],
              *ence_g  = (const float*)d_in[i++], *ence_be = (const float*)d_in[i++];
  const float *msg_W0 = (const float*)d_in[i++], *msg_b0 = (const float*)d_in[i++],
              *msg_W1 = (const float*)d_in[i++], *msg_b1 = (const float*)d_in[i++],
              *msg_W2 = (const float*)d_in[i++], *msg_b2 = (const float*)d_in[i++],
              *msg_g  = (const float*)d_in[i++], *msg_be = (const float*)d_in[i++];
  const float *upd_W0 = (const float*)d_in[i++], *upd_b0 = (const float*)d_in[i++],
              *upd_W1 = (const float*)d_in[i++], *upd_b1 = (const float*)d_in[i++],
              *upd_W2 = (const float*)d_in[i++], *upd_b2 = (const float*)d_in[i++],
              *upd_g  = (const float*)d_in[i++], *upd_be = (const float*)d_in[i++];
  const float *dec_W0 = (const float*)d_in[i++], *dec_b0 = (const float*)d_in[i++],
              *dec_W1 = (const float*)d_in[i++], *dec_b1 = (const float*)d_in[i++],
              *dec_W2 = (const float*)d_in[i++], *dec_b2 = (const float*)d_in[i++];

  // workspace layout (~70 MB)
  char* w = (char*)d_ws;
  float* h      = (float*)w;            w += (size_t)NN * 128 * 4;
  float* pooled = (float*)w;            w += (size_t)NN * 128 * 4;
  float* Ur     = (float*)w;            w += (size_t)NN * 128 * 4;
  float* Us     = (float*)w;            w += (size_t)NN * 128 * 4;
  u16*   h_bf   = (u16*)w;              w += (size_t)NN * 128 * 2;
  u16*   e_bf   = (u16*)w;              w += (size_t)EE * 128 * 2;
  u16*   m_buf  = (u16*)w;              w += (size_t)EE * 128 * 2;
  u16*   mWt0e  = (u16*)w;              w += (size_t)10 * 128 * 128 * 2;
  u16*   mWt1   = (u16*)w;              w += (size_t)10 * 128 * 128 * 2;
  u16*   mWt2   = (u16*)w;              w += (size_t)10 * 128 * 128 * 2;
  u16*   pWtr   = (u16*)w;              w += (size_t)10 * 128 * 128 * 2;
  u16*   pWts   = (u16*)w;              w += (size_t)10 * 128 * 128 * 2;
  u16*   uWt0   = (u16*)w;              w += (size_t)10 * 128 * 256 * 2;
  u16*   uWt1   = (u16*)w;              w += (size_t)10 * 128 * 128 * 2;
  u16*   uWt2   = (u16*)w;              w += (size_t)10 * 128 * 128 * 2;
  u16*   nWt0   = (u16*)w;              w += (size_t)128 * 64 * 2;
  u16*   nWt1   = (u16*)w;              w += (size_t)128 * 128 * 2;
  u16*   nWt2   = (u16*)w;              w += (size_t)128 * 128 * 2;
  u16*   eWt0   = (u16*)w;              w += (size_t)128 * 64 * 2;
  u16*   eWt1   = (u16*)w;              w += (size_t)128 * 128 * 2;
  u16*   eWt2   = (u16*)w;              w += (size_t)128 * 128 * 2;
  int*   cnt    = (int*)w;              w += (size_t)NN * 4;
  int*   offs   = (int*)w;              w += (size_t)(NN + 1) * 4;
  int*   curs   = (int*)w;              w += (size_t)NN * 4;
  int*   sortp  = (int*)w;              w += (size_t)EE * 4;
  int*   rcv_s  = (int*)w;              w += (size_t)EE * 4;
  int*   snd_s  = (int*)w;              w += (size_t)EE * 4;

  const int NB_N64 = (NN + 63) / 64;     // 157
  const int NB_E128 = EE / 128;          // 625
  const int NB_E256 = (EE + 255) / 256;

  // CSR build (once per launch)
  hipMemsetAsync(cnt, 0, (size_t)NN * 4, stream);
  hist_k<<<NB_E256, 256, 0, stream>>>(receivers, cnt);
  scan_k<<<1, 1024, 0, stream>>>(cnt, offs, curs);
  scatter_k<<<NB_E256, 256, 0, stream>>>(receivers, senders, curs, sortp, rcv_s, snd_s);

  // weight pre-transposes (bf16 W^T). msg W0 split: rows 0-127 rcv, 128-255 snd, 256-383 e
  wtrans_k<<<10 * 4 * 4, 256, 0, stream>>>(msg_W0,             pWtr,  128, 384 * 128);
  wtrans_k<<<10 * 4 * 4, 256, 0, stream>>>(msg_W0 + 128 * 128, pWts,  128, 384 * 128);
  wtrans_k<<<10 * 4 * 4, 256, 0, stream>>>(msg_W0 + 256 * 128, mWt0e, 128, 384 * 128);
  wtrans_k<<<10 * 4 * 4, 256, 0, stream>>>(msg_W1, mWt1, 128, 128 * 128);
  wtrans_k<<<10 * 4 * 4, 256, 0, stream>>>(msg_W2, mWt2, 128, 128 * 128);
  wtrans_k<<<10 * 8 * 4, 256, 0, stream>>>(upd_W0, uWt0, 256, 256 * 128);
  wtrans_k<<<10 * 4 * 4, 256, 0, stream>>>(upd_W1, uWt1, 128, 128 * 128);
  wtrans_k<<<10 * 4 * 4, 256, 0, stream>>>(upd_W2, uWt2, 128, 128 * 128);
  wtrans_pad_k<<<1, 128, 0, stream>>>(encn_W0, nWt0, 30);
  wtrans_k<<<4 * 4, 256, 0, stream>>>(encn_W1, nWt1, 128, 128 * 128);
  wtrans_k<<<4 * 4, 256, 0, stream>>>(encn_W2, nWt2, 128, 128 * 128);
  wtrans_pad_k<<<1, 128, 0, stream>>>(ence_W0, eWt0, 3);
  wtrans_k<<<4 * 4, 256, 0, stream>>>(ence_W1, eWt1, 128, 128 * 128);
  wtrans_k<<<4 * 4, 256, 0, stream>>>(ence_W2, eWt2, 128, 128 * 128);

  // node encoder (+ U-emit for round 0)
  mlp3_mfma_k<2, 1, 64><<<NB_N64, 256, 0, stream>>>(
      nullptr, nullptr, nullptr, nullptr, node_feat, nullptr, nullptr, nullptr,
      nullptr, nullptr,
      nWt0, encn_b0, nWt1, encn_b1, nWt2, encn_b2, encn_g, encn_be,
      pWtr, pWts, msg_b0,
      nullptr, h, h_bf, Ur, Us);
  // edge encoder (scatter into receiver-sorted e_bf)
  mlp3_mfma_k<3, 1, 128><<<NB_E128, 256, 0, stream>>>(
      nullptr, nullptr, nullptr, nullptr, edge_feat, nullptr, nullptr, sortp,
      nullptr, nullptr,
      eWt0, ence_b0, eWt1, ence_b1, eWt2, ence_b2, ence_g, ence_be,
      nullptr, nullptr, nullptr,
      nullptr, nullptr, e_bf, nullptr, nullptr);

  for (int t = 0; t < TT; ++t) {
    mlp3_mfma_k<0, 2, 128><<<NB_E128, 256, 0, stream>>>(
        nullptr, e_bf, nullptr, nullptr, nullptr, snd_s, rcv_s, nullptr,
        Ur, Us,
        mWt0e + (size_t)t * 128 * 128, nullptr,
        mWt1  + (size_t)t * 128 * 128, msg_b1 + (size_t)t * 128,
        mWt2  + (size_t)t * 128 * 128, msg_b2 + (size_t)t * 128,
        msg_g + (size_t)t * 128, msg_be + (size_t)t * 128,
        nullptr, nullptr, nullptr,
        m_buf, nullptr, nullptr, nullptr, nullptr);
    pool_k<<<NN / 4, 256, 0, stream>>>(m_buf, offs, pooled);
    bool last = (t == TT - 1);
    mlp3_mfma_k<1, 4, 64><<<NB_N64, 256, 0, stream>>>(
        h_bf, nullptr, h, pooled, nullptr, nullptr, nullptr, nullptr,
        nullptr, nullptr,
        uWt0 + (size_t)t * 128 * 256, upd_b0 + (size_t)t * 128,
        uWt1 + (size_t)t * 128 * 128, upd_b1 + (size_t)t * 128,
        uWt2 + (size_t)t * 128 * 128, upd_b2 + (size_t)t * 128,
        upd_g + (size_t)t * 128, upd_be + (size_t)t * 128,
        last ? nullptr : (pWtr + (size_t)(t + 1) * 128 * 128),
        last ? nullptr : (pWts + (size_t)(t + 1) * 128 * 128),
        last ? nullptr : (msg_b0 + (size_t)(t + 1) * 128),
        nullptr, h, h_bf, Ur, Us);
  }
  dec_k<<<(NN + 31) / 32, 256, 0, stream>>>(h, dec_W0, dec_b0, dec_W1, dec_b1,
                                            dec_W2, dec_b2, (float*)d_out);
}